// Round 2
// baseline (324.270 us; speedup 1.0000x reference)
//
#include <hip/hip_runtime.h>

typedef unsigned short u16;
typedef __attribute__((ext_vector_type(4))) float f32x4;
typedef __attribute__((ext_vector_type(8))) short bf16x8;
typedef __attribute__((ext_vector_type(4))) unsigned short u16x4;
typedef __attribute__((ext_vector_type(8))) unsigned short u16x8;

#define S_LEN 2048
#define DMODEL 1024

__device__ __forceinline__ float bf2f(u16 u) {
  union { unsigned int i; float f; } c; c.i = ((unsigned int)u) << 16; return c.f;
}
__device__ __forceinline__ u16 f2bf(float f) {
  union { float f; unsigned int i; } c; c.f = f;
  unsigned int v = c.i + 0x7FFFu + ((c.i >> 16) & 1u);
  return (u16)(v >> 16);
}

typedef const __attribute__((address_space(1))) void gv_t;
typedef __attribute__((address_space(3))) void lv_t;
__device__ __forceinline__ void gload_lds16(const void* g, void* l) {
  __builtin_amdgcn_global_load_lds((gv_t*)g, (lv_t*)l, 16, 0, 0);
}

// ---------------- f32 -> bf16 convert (8 elements/thread) ----------------
__global__ __launch_bounds__(256) void k_cvt(const float* __restrict__ src,
                                             u16* __restrict__ dst, int n8) {
  int i = blockIdx.x * 256 + threadIdx.x;
  if (i >= n8) return;
  f32x4 a = ((const f32x4*)src)[i * 2];
  f32x4 b = ((const f32x4*)src)[i * 2 + 1];
  u16x8 o;
#pragma unroll
  for (int j = 0; j < 4; ++j) { o[j] = f2bf(a[j]); o[j + 4] = f2bf(b[j]); }
  ((u16x8*)dst)[i] = o;
}

// ---------------- weight transpose+convert: dst[c*R+r] = bf16(src[r*C+c]) ----------------
__global__ __launch_bounds__(256) void k_twcvt(const float* __restrict__ src,
                                               u16* __restrict__ dst, int R, int C) {
  __shared__ u16 tile[64][68];
  int tiles_c = C >> 6;
  int tr = blockIdx.x / tiles_c, tc = blockIdx.x - tr * tiles_c;
  int r0 = tr << 6, c0 = tc << 6;
  int t = threadIdx.x;
#pragma unroll
  for (int i = 0; i < 4; ++i) {
    int e = (t + i * 256) << 2;
    int rr = e >> 6, cc = e & 63;
    f32x4 v = *(const f32x4*)&src[(size_t)(r0 + rr) * C + (c0 + cc)];
#pragma unroll
    for (int j = 0; j < 4; ++j) tile[rr][cc + j] = f2bf(v[j]);
  }
  __syncthreads();
#pragma unroll
  for (int i = 0; i < 4; ++i) {
    int e = (t + i * 256) << 2;
    int rr = e >> 6, cc = e & 63;
    u16x4 v;
#pragma unroll
    for (int j = 0; j < 4; ++j) v[j] = tile[cc + j][rr];
    *(u16x4*)&dst[(size_t)(c0 + rr) * R + (r0 + cc)] = v;
  }
}

// ---------------- bf16 transpose (for V) ----------------
__global__ __launch_bounds__(256) void k_transpose(const u16* __restrict__ src,
                                                   u16* __restrict__ dst,
                                                   int R, int C) {
  __shared__ u16 tile[64][68];
  int tiles_c = C >> 6;
  int tr = blockIdx.x / tiles_c, tc = blockIdx.x - tr * tiles_c;
  int r0 = tr << 6, c0 = tc << 6;
  int t = threadIdx.x;
#pragma unroll
  for (int i = 0; i < 4; ++i) {
    int e = (t + i * 256) << 2;
    int rr = e >> 6, cc = e & 63;
    u16x4 v = *(const u16x4*)&src[(size_t)(r0 + rr) * C + (c0 + cc)];
#pragma unroll
    for (int j = 0; j < 4; ++j) tile[rr][cc + j] = v[j];
  }
  __syncthreads();
#pragma unroll
  for (int i = 0; i < 4; ++i) {
    int e = (t + i * 256) << 2;
    int rr = e >> 6, cc = e & 63;
    u16x4 v;
#pragma unroll
    for (int j = 0; j < 4; ++j) v[j] = tile[cc + j][rr];
    *(u16x4*)&dst[(size_t)(c0 + rr) * R + (r0 + cc)] = v;
  }
}

// ---------------- GEMM: C[M,N] = A[M,K]*Bt[N,K]^T + bias, 128x128 tile ----------------
struct GemmSet { const u16* A; const u16* Bt; const float* bias; void* C; };
struct GemmArgs { GemmSet s[3]; };

template <int OUTF32>
__global__ __launch_bounds__(256) void k_gemm_bt(GemmArgs ga) {
  constexpr int K = 1024, N = 1024;
  __shared__ __align__(16) u16 Al[128 * 32];
  __shared__ __align__(16) u16 Bl[128 * 32];
  int mat = blockIdx.x >> 8;
  int t = blockIdx.x & 255;
  int m0 = (t & 31) << 7;
  int n0 = (t >> 5) << 7;
  const u16* A = ga.s[mat].A;
  const u16* Bt = ga.s[mat].Bt;
  int lane = threadIdx.x & 63, w = threadIdx.x >> 6;
  int g = lane >> 4, cl = lane & 15;
  int wr = w >> 1, wc = w & 1;
  f32x4 zero4 = {0.f, 0.f, 0.f, 0.f};
  f32x4 acc[4][4];
#pragma unroll
  for (int i = 0; i < 4; ++i)
#pragma unroll
    for (int j = 0; j < 4; ++j) acc[i][j] = zero4;

  int srow0 = w * 32 + (lane >> 2);
  int scol = (lane & 3) << 3;
  for (int kt = 0; kt < K / 32; ++kt) {
    int k0 = kt << 5;
#pragma unroll
    for (int c = 0; c < 2; ++c) {
      int row = srow0 + c * 16;
      gload_lds16(&A[(size_t)(m0 + row) * K + k0 + scol], &Al[w * 1024 + c * 512]);
      gload_lds16(&Bt[(size_t)(n0 + row) * K + k0 + scol], &Bl[w * 1024 + c * 512]);
    }
    __syncthreads();
    bf16x8 af[4], bfm[4];
#pragma unroll
    for (int i = 0; i < 4; ++i) {
      af[i]  = *(const bf16x8*)&Al[(wr * 64 + i * 16 + cl) * 32 + g * 8];
      bfm[i] = *(const bf16x8*)&Bl[(wc * 64 + i * 16 + cl) * 32 + g * 8];
    }
#pragma unroll
    for (int mi = 0; mi < 4; ++mi)
#pragma unroll
      for (int ni = 0; ni < 4; ++ni)
        acc[mi][ni] = __builtin_amdgcn_mfma_f32_16x16x32_bf16(af[mi], bfm[ni], acc[mi][ni], 0, 0, 0);
    __syncthreads();
  }
  const float* bias = ga.s[mat].bias;
#pragma unroll
  for (int ni = 0; ni < 4; ++ni) {
    int n = n0 + wc * 64 + ni * 16 + cl;
    float bv = bias[n];
#pragma unroll
    for (int mi = 0; mi < 4; ++mi) {
      int r0 = m0 + wr * 64 + mi * 16 + g * 4;
#pragma unroll
      for (int r = 0; r < 4; ++r) {
        float val = acc[mi][ni][r] + bv;
        if (OUTF32) ((float*)ga.s[mat].C)[(size_t)(r0 + r) * N + n] = val;
        else        ((u16*)ga.s[mat].C)[(size_t)(r0 + r) * N + n] = f2bf(val);
      }
    }
  }
}

// ---------------- flash attention ----------------
// Q,K: [B,S,1024] bf16 token-major (head = 64-ch slice). Vt: [B,1024,S] bf16. O: [B,S,1024] bf16.
__global__ __launch_bounds__(256) void k_attn(const u16* __restrict__ Q,
                                              const u16* __restrict__ Kc,
                                              const u16* __restrict__ Vt,
                                              u16* __restrict__ O) {
  __shared__ __align__(16) u16 P_lds[4][32 * 64];
  int lane = threadIdx.x & 63, w = threadIdx.x >> 6;
  int g = lane >> 4, cl = lane & 15;
  int bx = blockIdx.x;
  int logical = (bx & 7) * 64 + (bx >> 3);   // group a head's q-tiles on one XCD
  int bh = logical >> 4, qt = logical & 15;
  int b = bh >> 4, h = bh & 15;
  const u16* Qb = Q + (size_t)b * S_LEN * DMODEL + h * 64;
  const u16* Kb = Kc + (size_t)b * S_LEN * DMODEL + h * 64;
  const u16* Vb = Vt + ((size_t)b * DMODEL + h * 64) * S_LEN;
  u16* Ob = O + (size_t)b * S_LEN * DMODEL + h * 64;
  int qr = qt * 128 + w * 32;

  // Q fragments, pre-scaled by 1/8 (exact exponent subtract)
  bf16x8 qf[2][2];
#pragma unroll
  for (int mt = 0; mt < 2; ++mt)
#pragma unroll
    for (int kk = 0; kk < 2; ++kk) {
      bf16x8 v = *(const bf16x8*)&Qb[(size_t)(qr + mt * 16 + cl) * DMODEL + kk * 32 + g * 8];
#pragma unroll
      for (int j = 0; j < 8; ++j) {
        u16 u = (u16)v[j];
        u16 e = (u16)(u & 0x7F80u);
        v[j] = (short)(e > 0x0180u ? (u16)(u - 0x0180u) : (u16)(u & 0x8000u));
      }
      qf[mt][kk] = v;
    }

  f32x4 zero4 = {0.f, 0.f, 0.f, 0.f};
  f32x4 oacc[2][4];
  float mrun[2][4], lrun[2][4];
#pragma unroll
  for (int mt = 0; mt < 2; ++mt) {
#pragma unroll
    for (int dt = 0; dt < 4; ++dt) oacc[mt][dt] = zero4;
#pragma unroll
    for (int r = 0; r < 4; ++r) { mrun[mt][r] = -3.0e38f; lrun[mt][r] = 0.f; }
  }

  u16* Pw = &P_lds[w][0];
  for (int kt = 0; kt < S_LEN / 64; ++kt) {
    bf16x8 kf[4][2];
#pragma unroll
    for (int nt = 0; nt < 4; ++nt)
#pragma unroll
      for (int kk = 0; kk < 2; ++kk)
        kf[nt][kk] = *(const bf16x8*)&Kb[(size_t)(kt * 64 + nt * 16 + cl) * DMODEL + kk * 32 + g * 8];

    f32x4 s[2][4];
#pragma unroll
    for (int mt = 0; mt < 2; ++mt)
#pragma unroll
      for (int nt = 0; nt < 4; ++nt) {
        f32x4 a0 = __builtin_amdgcn_mfma_f32_16x16x32_bf16(qf[mt][0], kf[nt][0], zero4, 0, 0, 0);
        s[mt][nt] = __builtin_amdgcn_mfma_f32_16x16x32_bf16(qf[mt][1], kf[nt][1], a0, 0, 0, 0);
      }

    // online softmax (wave-parallel: reduce across the 16 col-lanes)
#pragma unroll
    for (int mt = 0; mt < 2; ++mt) {
#pragma unroll
      for (int r = 0; r < 4; ++r) {
        float tm = fmaxf(fmaxf(s[mt][0][r], s[mt][1][r]), fmaxf(s[mt][2][r], s[mt][3][r]));
#pragma unroll
        for (int d = 1; d < 16; d <<= 1) tm = fmaxf(tm, __shfl_xor(tm, d, 64));
        float mnew = fmaxf(mrun[mt][r], tm);
        float alpha = __expf(mrun[mt][r] - mnew);
        mrun[mt][r] = mnew;
        float rs = 0.f;
#pragma unroll
        for (int nt = 0; nt < 4; ++nt) {
          float p = __expf(s[mt][nt][r] - mnew);
          s[mt][nt][r] = p;
          rs += p;
        }
#pragma unroll
        for (int d = 1; d < 16; d <<= 1) rs += __shfl_xor(rs, d, 64);
        lrun[mt][r] = lrun[mt][r] * alpha + rs;
#pragma unroll
        for (int dt = 0; dt < 4; ++dt) oacc[mt][dt][r] *= alpha;
      }
    }

    // P (D-layout) -> per-wave LDS, XOR-swizzled 16B chunks
#pragma unroll
    for (int mt = 0; mt < 2; ++mt)
#pragma unroll
      for (int nt = 0; nt < 4; ++nt)
#pragma unroll
        for (int r = 0; r < 4; ++r) {
          int row = mt * 16 + g * 4 + r;
          int col = nt * 16 + cl;
          int ch = (col >> 3) ^ (row & 7);
          Pw[row * 64 + ch * 8 + (col & 7)] = f2bf(s[mt][nt][r]);
        }
    __asm__ volatile("s_waitcnt lgkmcnt(0)" ::: "memory");
    __builtin_amdgcn_sched_barrier(0);

    // P as A-fragments, V as B-fragments
    bf16x8 pf[2][2], vf[4][2];
#pragma unroll
    for (int mt = 0; mt < 2; ++mt)
#pragma unroll
      for (int kk2 = 0; kk2 < 2; ++kk2) {
        int row = mt * 16 + cl;
        int ch = (kk2 * 4 + g) ^ (row & 7);
        pf[mt][kk2] = *(const bf16x8*)&Pw[row * 64 + ch * 8];
      }
#pragma unroll
    for (int dt = 0; dt < 4; ++dt)
#pragma unroll
      for (int kk2 = 0; kk2 < 2; ++kk2)
        vf[dt][kk2] = *(const bf16x8*)&Vb[(size_t)(dt * 16 + cl) * S_LEN + kt * 64 + kk2 * 32 + g * 8];
#pragma unroll
    for (int mt = 0; mt < 2; ++mt)
#pragma unroll
      for (int dt = 0; dt < 4; ++dt) {
        oacc[mt][dt] = __builtin_amdgcn_mfma_f32_16x16x32_bf16(pf[mt][0], vf[dt][0], oacc[mt][dt], 0, 0, 0);
        oacc[mt][dt] = __builtin_amdgcn_mfma_f32_16x16x32_bf16(pf[mt][1], vf[dt][1], oacc[mt][dt], 0, 0, 0);
      }
  }

  float inv[2][4];
#pragma unroll
  for (int mt = 0; mt < 2; ++mt)
#pragma unroll
    for (int r = 0; r < 4; ++r) inv[mt][r] = 1.0f / lrun[mt][r];
#pragma unroll
  for (int mt = 0; mt < 2; ++mt)
#pragma unroll
    for (int dt = 0; dt < 4; ++dt)
#pragma unroll
      for (int r = 0; r < 4; ++r) {
        int row = qr + mt * 16 + g * 4 + r;
        Ob[(size_t)row * DMODEL + dt * 16 + cl] = f2bf(oacc[mt][dt][r] * inv[mt][r]);
      }
}

// ---------------- host ----------------
extern "C" void kernel_launch(void* const* d_in, const int* in_sizes, int n_in,
                              void* d_out, int out_size, void* d_ws, size_t ws_size,
                              hipStream_t stream) {
  const float* q  = (const float*)d_in[0];
  const float* k  = (const float*)d_in[1];
  const float* v  = (const float*)d_in[2];
  const float* Wq = (const float*)d_in[3];
  const float* bq = (const float*)d_in[4];
  const float* Wk = (const float*)d_in[5];
  const float* bk = (const float*)d_in[6];
  const float* Wv = (const float*)d_in[7];
  const float* bv = (const float*)d_in[8];
  const float* Wo = (const float*)d_in[9];
  const float* bo = (const float*)d_in[10];
  float* out = (float*)d_out;
  char* ws = (char*)d_ws;
  const size_t MB = 1024 * 1024;
  u16* wtq = (u16*)(ws + 0 * MB);
  u16* wtk = (u16*)(ws + 2 * MB);
  u16* wtv = (u16*)(ws + 4 * MB);
  u16* wto = (u16*)(ws + 6 * MB);
  u16* qb  = (u16*)(ws + 8 * MB);   // bf16 q  (later reused as Vt)
  u16* kb  = (u16*)(ws + 16 * MB);  // bf16 k  (later reused as O)
  u16* vb  = (u16*)(ws + 24 * MB);  // bf16 v
  u16* Cq  = (u16*)(ws + 32 * MB);
  u16* Ck  = (u16*)(ws + 40 * MB);
  u16* Cv  = (u16*)(ws + 48 * MB);
  u16* Vt  = qb;                    // alias: qb dead after QKV GEMM
  u16* O   = kb;                    // alias: kb dead after QKV GEMM

  const int NTOK = 2 * S_LEN * DMODEL;      // 4,194,304
  k_cvt<<<NTOK / 8 / 256, 256, 0, stream>>>(q, qb, NTOK / 8);
  k_cvt<<<NTOK / 8 / 256, 256, 0, stream>>>(k, kb, NTOK / 8);
  k_cvt<<<NTOK / 8 / 256, 256, 0, stream>>>(v, vb, NTOK / 8);

  k_twcvt<<<256, 256, 0, stream>>>(Wq, wtq, 1024, 1024);
  k_twcvt<<<256, 256, 0, stream>>>(Wk, wtk, 1024, 1024);
  k_twcvt<<<256, 256, 0, stream>>>(Wv, wtv, 1024, 1024);
  k_twcvt<<<256, 256, 0, stream>>>(Wo, wto, 1024, 1024);

  GemmArgs ga;
  ga.s[0] = {qb, wtq, bq, (void*)Cq};
  ga.s[1] = {kb, wtk, bk, (void*)Ck};
  ga.s[2] = {vb, wtv, bv, (void*)Cv};
  k_gemm_bt<0><<<768, 256, 0, stream>>>(ga);

  k_transpose<<<512, 256, 0, stream>>>(Cv, Vt, 2048, 1024);
  k_transpose<<<512, 256, 0, stream>>>(Cv + (size_t)2048 * 1024, Vt + (size_t)1024 * 2048, 2048, 1024);

  k_attn<<<512, 256, 0, stream>>>(Cq, Ck, Vt, O);

  GemmArgs go;
  go.s[0] = {O, wto, bo, (void*)out};
  go.s[1] = go.s[0];
  go.s[2] = go.s[0];
  k_gemm_bt<1><<<256, 256, 0, stream>>>(go);
}

// Round 3
// 320.459 us; speedup vs baseline: 1.0119x; 1.0119x over previous
//
#include <hip/hip_runtime.h>

typedef unsigned short u16;
typedef unsigned int u32;
typedef __attribute__((ext_vector_type(4))) float f32x4;
typedef __attribute__((ext_vector_type(16))) float f32x16;
typedef __attribute__((ext_vector_type(8))) short bf16x8;
typedef __attribute__((ext_vector_type(4))) unsigned short u16x4;
typedef __attribute__((ext_vector_type(8))) unsigned short u16x8;
typedef __attribute__((ext_vector_type(4))) unsigned int u32x4;

#define S_LEN 2048
#define DMODEL 1024

__device__ __forceinline__ float bf2f(u16 u) {
  union { unsigned int i; float f; } c; c.i = ((unsigned int)u) << 16; return c.f;
}
__device__ __forceinline__ u16 f2bf(float f) {
  union { float f; unsigned int i; } c; c.f = f;
  unsigned int v = c.i + 0x7FFFu + ((c.i >> 16) & 1u);
  return (u16)(v >> 16);
}
__device__ __forceinline__ u32 cvtpk(float lo, float hi) {
  u32 r;
  asm("v_cvt_pk_bf16_f32 %0, %1, %2" : "=v"(r) : "v"(lo), "v"(hi));
  return r;
}

typedef const __attribute__((address_space(1))) void gv_t;
typedef __attribute__((address_space(3))) void lv_t;
__device__ __forceinline__ void gload_lds16(const void* g, void* l) {
  __builtin_amdgcn_global_load_lds((gv_t*)g, (lv_t*)l, 16, 0, 0);
}

// ---------------- f32 -> bf16 convert (8 elements/thread) ----------------
__global__ __launch_bounds__(256) void k_cvt(const float* __restrict__ src,
                                             u16* __restrict__ dst, int n8) {
  int i = blockIdx.x * 256 + threadIdx.x;
  if (i >= n8) return;
  f32x4 a = ((const f32x4*)src)[i * 2];
  f32x4 b = ((const f32x4*)src)[i * 2 + 1];
  u16x8 o;
#pragma unroll
  for (int j = 0; j < 4; ++j) { o[j] = f2bf(a[j]); o[j + 4] = f2bf(b[j]); }
  ((u16x8*)dst)[i] = o;
}

// ---------------- weight transpose+convert: dst[c*R+r] = bf16(src[r*C+c]) ----------------
__global__ __launch_bounds__(256) void k_twcvt(const float* __restrict__ src,
                                               u16* __restrict__ dst, int R, int C) {
  __shared__ u16 tile[64][68];
  int tiles_c = C >> 6;
  int tr = blockIdx.x / tiles_c, tc = blockIdx.x - tr * tiles_c;
  int r0 = tr << 6, c0 = tc << 6;
  int t = threadIdx.x;
#pragma unroll
  for (int i = 0; i < 4; ++i) {
    int e = (t + i * 256) << 2;
    int rr = e >> 6, cc = e & 63;
    f32x4 v = *(const f32x4*)&src[(size_t)(r0 + rr) * C + (c0 + cc)];
#pragma unroll
    for (int j = 0; j < 4; ++j) tile[rr][cc + j] = f2bf(v[j]);
  }
  __syncthreads();
#pragma unroll
  for (int i = 0; i < 4; ++i) {
    int e = (t + i * 256) << 2;
    int rr = e >> 6, cc = e & 63;
    u16x4 v;
#pragma unroll
    for (int j = 0; j < 4; ++j) v[j] = tile[cc + j][rr];
    *(u16x4*)&dst[(size_t)(c0 + rr) * R + (r0 + cc)] = v;
  }
}

// ---------------- bf16 transpose (for V) ----------------
__global__ __launch_bounds__(256) void k_transpose(const u16* __restrict__ src,
                                                   u16* __restrict__ dst,
                                                   int R, int C) {
  __shared__ u16 tile[64][68];
  int tiles_c = C >> 6;
  int tr = blockIdx.x / tiles_c, tc = blockIdx.x - tr * tiles_c;
  int r0 = tr << 6, c0 = tc << 6;
  int t = threadIdx.x;
#pragma unroll
  for (int i = 0; i < 4; ++i) {
    int e = (t + i * 256) << 2;
    int rr = e >> 6, cc = e & 63;
    u16x4 v = *(const u16x4*)&src[(size_t)(r0 + rr) * C + (c0 + cc)];
#pragma unroll
    for (int j = 0; j < 4; ++j) tile[rr][cc + j] = v[j];
  }
  __syncthreads();
#pragma unroll
  for (int i = 0; i < 4; ++i) {
    int e = (t + i * 256) << 2;
    int rr = e >> 6, cc = e & 63;
    u16x4 v;
#pragma unroll
    for (int j = 0; j < 4; ++j) v[j] = tile[cc + j][rr];
    *(u16x4*)&dst[(size_t)(c0 + rr) * R + (r0 + cc)] = v;
  }
}

// ---------------- GEMM: C[M,N] = A[M,K]*Bt[N,K]^T + bias, 128x128 tile ----------------
struct GemmSet { const u16* A; const u16* Bt; const float* bias; void* C; };
struct GemmArgs { GemmSet s[3]; };

template <int OUTF32>
__global__ __launch_bounds__(256) void k_gemm_bt(GemmArgs ga) {
  constexpr int K = 1024, N = 1024;
  __shared__ __align__(16) u16 Al[128 * 32];
  __shared__ __align__(16) u16 Bl[128 * 32];
  int mat = blockIdx.x >> 8;
  int t = blockIdx.x & 255;
  int m0 = (t & 31) << 7;
  int n0 = (t >> 5) << 7;
  const u16* A = ga.s[mat].A;
  const u16* Bt = ga.s[mat].Bt;
  int lane = threadIdx.x & 63, w = threadIdx.x >> 6;
  int g = lane >> 4, cl = lane & 15;
  int wr = w >> 1, wc = w & 1;
  f32x4 zero4 = {0.f, 0.f, 0.f, 0.f};
  f32x4 acc[4][4];
#pragma unroll
  for (int i = 0; i < 4; ++i)
#pragma unroll
    for (int j = 0; j < 4; ++j) acc[i][j] = zero4;

  int srow0 = w * 32 + (lane >> 2);
  int scol = (lane & 3) << 3;
  for (int kt = 0; kt < K / 32; ++kt) {
    int k0 = kt << 5;
#pragma unroll
    for (int c = 0; c < 2; ++c) {
      int row = srow0 + c * 16;
      gload_lds16(&A[(size_t)(m0 + row) * K + k0 + scol], &Al[w * 1024 + c * 512]);
      gload_lds16(&Bt[(size_t)(n0 + row) * K + k0 + scol], &Bl[w * 1024 + c * 512]);
    }
    __syncthreads();
    bf16x8 af[4], bfm[4];
#pragma unroll
    for (int i = 0; i < 4; ++i) {
      af[i]  = *(const bf16x8*)&Al[(wr * 64 + i * 16 + cl) * 32 + g * 8];
      bfm[i] = *(const bf16x8*)&Bl[(wc * 64 + i * 16 + cl) * 32 + g * 8];
    }
#pragma unroll
    for (int mi = 0; mi < 4; ++mi)
#pragma unroll
      for (int ni = 0; ni < 4; ++ni)
        acc[mi][ni] = __builtin_amdgcn_mfma_f32_16x16x32_bf16(af[mi], bfm[ni], acc[mi][ni], 0, 0, 0);
    __syncthreads();
  }
  const float* bias = ga.s[mat].bias;
#pragma unroll
  for (int ni = 0; ni < 4; ++ni) {
    int n = n0 + wc * 64 + ni * 16 + cl;
    float bv = bias[n];
#pragma unroll
    for (int mi = 0; mi < 4; ++mi) {
      int r0 = m0 + wr * 64 + mi * 16 + g * 4;
#pragma unroll
      for (int r = 0; r < 4; ++r) {
        float val = acc[mi][ni][r] + bv;
        if (OUTF32) ((float*)ga.s[mat].C)[(size_t)(r0 + r) * N + n] = val;
        else        ((u16*)ga.s[mat].C)[(size_t)(r0 + r) * N + n] = f2bf(val);
      }
    }
  }
}

// ---------------- flash attention, 32x32 swapped-QK^T structure ----------------
// Q,K: [B,S,1024] bf16 token-major. Vt: [B,1024,S] bf16. O: [B,S,1024] bf16.
// Per wave: 32 q-rows. S^T = mfma(K, Q) so each lane owns one q-row's scores.
__global__ __launch_bounds__(256) void k_attn2(const u16* __restrict__ Q,
                                               const u16* __restrict__ Kc,
                                               const u16* __restrict__ Vt,
                                               u16* __restrict__ O) {
  int lane = threadIdx.x & 63, w = threadIdx.x >> 6;
  int l31 = lane & 31, hi = lane >> 5;
  int bx = blockIdx.x;
  int logical = (bx & 7) * 64 + (bx >> 3);   // group a head's q-tiles on one XCD
  int bh = logical >> 4, qt = logical & 15;
  int b = bh >> 4, h = bh & 15;
  const u16* Qb = Q + (size_t)b * S_LEN * DMODEL + h * 64;
  const u16* Kb = Kc + (size_t)b * S_LEN * DMODEL + h * 64;
  const u16* Vb = Vt + ((size_t)b * DMODEL + h * 64) * S_LEN;
  u16* Ob = O + (size_t)b * S_LEN * DMODEL + h * 64;
  int qbase = qt * 128 + w * 32;

  // Q as B-fragments: lane holds Q[qbase+l31][kd*16 + hi*8 + j], kd=0..3
  bf16x8 qf[4];
  const u16* qp = &Qb[(size_t)(qbase + l31) * DMODEL + hi * 8];
#pragma unroll
  for (int kd = 0; kd < 4; ++kd) qf[kd] = *(const bf16x8*)&qp[kd * 16];

  f32x16 zero16 = {0};
  f32x16 oa0 = zero16, oa1 = zero16;
  float m = -3.0e38f, lsum = 0.f;
  const float INVSQ = 0.125f;  // 1/sqrt(64)

  const u16* kp = Kb + (size_t)l31 * DMODEL + hi * 8;   // K row base for this lane
  const u16* vp = Vb + (size_t)l31 * S_LEN + hi * 8;    // V^T row base (dv = l31)

  for (int kt = 0; kt < S_LEN / 64; ++kt) {
    int kv0 = kt * 64;
    // V B-fragments for this kv block (issue early)
    bf16x8 vf0[4], vf1[4];
    const u16* vpa = vp + kv0;
    const u16* vpb = vp + 32 * S_LEN + kv0;
#pragma unroll
    for (int ks = 0; ks < 4; ++ks) {
      vf0[ks] = *(const bf16x8*)&vpa[ks * 16];
      vf1[ks] = *(const bf16x8*)&vpb[ks * 16];
    }
    // QK^T: S^T tiles (kv x q), A = K rows, B = Q
    f32x16 s0 = zero16, s1 = zero16;
    const u16* kpa = kp + (size_t)kv0 * DMODEL;
    const u16* kpb = kpa + 32 * DMODEL;
#pragma unroll
    for (int kd = 0; kd < 4; ++kd) {
      bf16x8 kfa = *(const bf16x8*)&kpa[kd * 16];
      bf16x8 kfb = *(const bf16x8*)&kpb[kd * 16];
      s0 = __builtin_amdgcn_mfma_f32_32x32x16_bf16(kfa, qf[kd], s0, 0, 0, 0);
      s1 = __builtin_amdgcn_mfma_f32_32x32x16_bf16(kfb, qf[kd], s1, 0, 0, 0);
    }

    // in-register row max (this lane's half of 64 kv values)
    float t0 = fmaxf(s0[0], s0[1]), t1 = fmaxf(s0[2], s0[3]);
    float t2 = fmaxf(s0[4], s0[5]), t3 = fmaxf(s0[6], s0[7]);
#pragma unroll
    for (int r = 8; r < 16; r += 4) {
      t0 = fmaxf(t0, fmaxf(s0[r], s0[r + 1]));
      t1 = fmaxf(t1, fmaxf(s0[r + 2], s0[r + 3]));
    }
#pragma unroll
    for (int r = 0; r < 16; r += 4) {
      t2 = fmaxf(t2, fmaxf(s1[r], s1[r + 1]));
      t3 = fmaxf(t3, fmaxf(s1[r + 2], s1[r + 3]));
    }
    float tm = fmaxf(fmaxf(t0, t1), fmaxf(t2, t3));

    // defer-max: rescale only when max grows beyond raw threshold 64 (p <= e^8)
    if (!__all(tm <= m + 64.0f)) {
      float tmf = fmaxf(tm, __shfl_xor(tm, 32, 64));
      float mnew = fmaxf(m, tmf);
      float alpha = __expf((m - mnew) * INVSQ);
#pragma unroll
      for (int r = 0; r < 16; ++r) {
        float ar = __shfl(alpha, ((r & 3) + 8 * (r >> 2)) + 4 * hi, 64);
        oa0[r] *= ar; oa1[r] *= ar;
      }
      lsum *= alpha;
      m = mnew;
    }

    // p = exp((s - m)/8), row sum
    float rs0 = 0.f, rs1 = 0.f;
#pragma unroll
    for (int r = 0; r < 16; ++r) {
      float p0 = __expf((s0[r] - m) * INVSQ);
      float p1 = __expf((s1[r] - m) * INVSQ);
      s0[r] = p0; s1[r] = p1;
      rs0 += p0; rs1 += p1;
    }
    float rs = rs0 + rs1;
    lsum += rs + __shfl_xor(rs, 32, 64);

    // pack P into PV A-fragments (kv = 16*ks + 8*hi + j per fragment)
    bf16x8 af[4];
    {
      u32 w0 = cvtpk(s0[0], s0[1]),  w1 = cvtpk(s0[2], s0[3]);
      u32 w2 = cvtpk(s0[4], s0[5]),  w3 = cvtpk(s0[6], s0[7]);
      u32 w4 = cvtpk(s0[8], s0[9]),  w5 = cvtpk(s0[10], s0[11]);
      u32 w6 = cvtpk(s0[12], s0[13]), w7 = cvtpk(s0[14], s0[15]);
      u32 x0 = __shfl_xor(w0, 32, 64), x1 = __shfl_xor(w1, 32, 64);
      u32 x2 = __shfl_xor(w2, 32, 64), x3 = __shfl_xor(w3, 32, 64);
      u32 x4 = __shfl_xor(w4, 32, 64), x5 = __shfl_xor(w5, 32, 64);
      u32 x6 = __shfl_xor(w6, 32, 64), x7 = __shfl_xor(w7, 32, 64);
      union { u32x4 u; bf16x8 v; } c0, c1;
      c0.u = u32x4{hi ? x2 : w0, hi ? x3 : w1, hi ? w2 : x0, hi ? w3 : x1};
      c1.u = u32x4{hi ? x6 : w4, hi ? x7 : w5, hi ? w6 : x4, hi ? w7 : x5};
      af[0] = c0.v; af[1] = c1.v;
    }
    {
      u32 w0 = cvtpk(s1[0], s1[1]),  w1 = cvtpk(s1[2], s1[3]);
      u32 w2 = cvtpk(s1[4], s1[5]),  w3 = cvtpk(s1[6], s1[7]);
      u32 w4 = cvtpk(s1[8], s1[9]),  w5 = cvtpk(s1[10], s1[11]);
      u32 w6 = cvtpk(s1[12], s1[13]), w7 = cvtpk(s1[14], s1[15]);
      u32 x0 = __shfl_xor(w0, 32, 64), x1 = __shfl_xor(w1, 32, 64);
      u32 x2 = __shfl_xor(w2, 32, 64), x3 = __shfl_xor(w3, 32, 64);
      u32 x4 = __shfl_xor(w4, 32, 64), x5 = __shfl_xor(w5, 32, 64);
      u32 x6 = __shfl_xor(w6, 32, 64), x7 = __shfl_xor(w7, 32, 64);
      union { u32x4 u; bf16x8 v; } c0, c1;
      c0.u = u32x4{hi ? x2 : w0, hi ? x3 : w1, hi ? w2 : x0, hi ? w3 : x1};
      c1.u = u32x4{hi ? x6 : w4, hi ? x7 : w5, hi ? w6 : x4, hi ? w7 : x5};
      af[2] = c0.v; af[3] = c1.v;
    }

    // PV: O += P * V   (A = P rows=q, B = V cols=dv)
#pragma unroll
    for (int ks = 0; ks < 4; ++ks) {
      oa0 = __builtin_amdgcn_mfma_f32_32x32x16_bf16(af[ks], vf0[ks], oa0, 0, 0, 0);
      oa1 = __builtin_amdgcn_mfma_f32_32x32x16_bf16(af[ks], vf1[ks], oa1, 0, 0, 0);
    }
  }

  // normalize and store: row q = qbase + (r&3)+8*(r>>2)+4*hi, col dv = nt*32 + l31
  float invl = 1.0f / lsum;
#pragma unroll
  for (int r = 0; r < 16; ++r) {
    float ir = __shfl(invl, ((r & 3) + 8 * (r >> 2)) + 4 * hi, 64);
    int row = qbase + ((r & 3) + 8 * (r >> 2)) + 4 * hi;
    Ob[(size_t)row * DMODEL + l31]      = f2bf(oa0[r] * ir);
    Ob[(size_t)row * DMODEL + 32 + l31] = f2bf(oa1[r] * ir);
  }
}

// ---------------- host ----------------
extern "C" void kernel_launch(void* const* d_in, const int* in_sizes, int n_in,
                              void* d_out, int out_size, void* d_ws, size_t ws_size,
                              hipStream_t stream) {
  const float* q  = (const float*)d_in[0];
  const float* k  = (const float*)d_in[1];
  const float* v  = (const float*)d_in[2];
  const float* Wq = (const float*)d_in[3];
  const float* bq = (const float*)d_in[4];
  const float* Wk = (const float*)d_in[5];
  const float* bk = (const float*)d_in[6];
  const float* Wv = (const float*)d_in[7];
  const float* bv = (const float*)d_in[8];
  const float* Wo = (const float*)d_in[9];
  const float* bo = (const float*)d_in[10];
  float* out = (float*)d_out;
  char* ws = (char*)d_ws;
  const size_t MB = 1024 * 1024;
  u16* wtq = (u16*)(ws + 0 * MB);
  u16* wtk = (u16*)(ws + 2 * MB);
  u16* wtv = (u16*)(ws + 4 * MB);
  u16* wto = (u16*)(ws + 6 * MB);
  u16* qb  = (u16*)(ws + 8 * MB);   // bf16 q  (later reused as Vt)
  u16* kb  = (u16*)(ws + 16 * MB);  // bf16 k  (later reused as O)
  u16* vb  = (u16*)(ws + 24 * MB);
  u16* Cq  = (u16*)(ws + 32 * MB);
  u16* Ck  = (u16*)(ws + 40 * MB);
  u16* Cv  = (u16*)(ws + 48 * MB);
  u16* Vt  = qb;                    // alias: qb dead after QKV GEMM
  u16* O   = kb;                    // alias: kb dead after QKV GEMM

  const int NTOK = 2 * S_LEN * DMODEL;      // 4,194,304
  k_cvt<<<NTOK / 8 / 256, 256, 0, stream>>>(q, qb, NTOK / 8);
  k_cvt<<<NTOK / 8 / 256, 256, 0, stream>>>(k, kb, NTOK / 8);
  k_cvt<<<NTOK / 8 / 256, 256, 0, stream>>>(v, vb, NTOK / 8);

  k_twcvt<<<256, 256, 0, stream>>>(Wq, wtq, 1024, 1024);
  k_twcvt<<<256, 256, 0, stream>>>(Wk, wtk, 1024, 1024);
  k_twcvt<<<256, 256, 0, stream>>>(Wv, wtv, 1024, 1024);
  k_twcvt<<<256, 256, 0, stream>>>(Wo, wto, 1024, 1024);

  GemmArgs ga;
  ga.s[0] = {qb, wtq, bq, (void*)Cq};
  ga.s[1] = {kb, wtk, bk, (void*)Ck};
  ga.s[2] = {vb, wtv, bv, (void*)Cv};
  k_gemm_bt<0><<<768, 256, 0, stream>>>(ga);

  k_transpose<<<512, 256, 0, stream>>>(Cv, Vt, 2048, 1024);
  k_transpose<<<512, 256, 0, stream>>>(Cv + (size_t)2048 * 1024, Vt + (size_t)1024 * 2048, 2048, 1024);

  k_attn2<<<512, 256, 0, stream>>>(Cq, Ck, Vt, O);

  GemmArgs go;
  go.s[0] = {O, wto, bo, (void*)out};
  go.s[1] = go.s[0];
  go.s[2] = go.s[0];
  k_gemm_bt<1><<<256, 256, 0, stream>>>(go);
}

// Round 4
// 273.196 us; speedup vs baseline: 1.1869x; 1.1730x over previous
//
#include <hip/hip_runtime.h>

typedef unsigned short u16;
typedef unsigned int u32;
typedef __attribute__((ext_vector_type(4))) float f32x4;
typedef __attribute__((ext_vector_type(16))) float f32x16;
typedef __attribute__((ext_vector_type(8))) short bf16x8;
typedef __attribute__((ext_vector_type(4))) unsigned short u16x4;
typedef __attribute__((ext_vector_type(8))) unsigned short u16x8;
typedef __attribute__((ext_vector_type(4))) unsigned int u32x4;

#define S_LEN 2048
#define DMODEL 1024

__device__ __forceinline__ float bf2f(u16 u) {
  union { unsigned int i; float f; } c; c.i = ((unsigned int)u) << 16; return c.f;
}
__device__ __forceinline__ u16 f2bf(float f) {
  union { float f; unsigned int i; } c; c.f = f;
  unsigned int v = c.i + 0x7FFFu + ((c.i >> 16) & 1u);
  return (u16)(v >> 16);
}
__device__ __forceinline__ u32 cvtpk(float lo, float hi) {
  u32 r;
  asm("v_cvt_pk_bf16_f32 %0, %1, %2" : "=v"(r) : "v"(lo), "v"(hi));
  return r;
}

typedef const __attribute__((address_space(1))) void gv_t;
typedef __attribute__((address_space(3))) void lv_t;
__device__ __forceinline__ void gload_lds16(const void* g, void* l) {
  __builtin_amdgcn_global_load_lds((gv_t*)g, (lv_t*)l, 16, 0, 0);
}

// ---------------- f32 -> bf16 convert (8 elements/thread) ----------------
__global__ __launch_bounds__(256) void k_cvt(const float* __restrict__ src,
                                             u16* __restrict__ dst, int n8) {
  int i = blockIdx.x * 256 + threadIdx.x;
  if (i >= n8) return;
  f32x4 a = ((const f32x4*)src)[i * 2];
  f32x4 b = ((const f32x4*)src)[i * 2 + 1];
  u16x8 o;
#pragma unroll
  for (int j = 0; j < 4; ++j) { o[j] = f2bf(a[j]); o[j + 4] = f2bf(b[j]); }
  ((u16x8*)dst)[i] = o;
}

// ---------------- weight transpose+convert: dst[c*R+r] = bf16(src[r*C+c]) ----------------
__global__ __launch_bounds__(256) void k_twcvt(const float* __restrict__ src,
                                               u16* __restrict__ dst, int R, int C) {
  __shared__ u16 tile[64][68];
  int tiles_c = C >> 6;
  int tr = blockIdx.x / tiles_c, tc = blockIdx.x - tr * tiles_c;
  int r0 = tr << 6, c0 = tc << 6;
  int t = threadIdx.x;
#pragma unroll
  for (int i = 0; i < 4; ++i) {
    int e = (t + i * 256) << 2;
    int rr = e >> 6, cc = e & 63;
    f32x4 v = *(const f32x4*)&src[(size_t)(r0 + rr) * C + (c0 + cc)];
#pragma unroll
    for (int j = 0; j < 4; ++j) tile[rr][cc + j] = f2bf(v[j]);
  }
  __syncthreads();
#pragma unroll
  for (int i = 0; i < 4; ++i) {
    int e = (t + i * 256) << 2;
    int rr = e >> 6, cc = e & 63;
    u16x4 v;
#pragma unroll
    for (int j = 0; j < 4; ++j) v[j] = tile[cc + j][rr];
    *(u16x4*)&dst[(size_t)(c0 + rr) * R + (r0 + cc)] = v;
  }
}

// ---------------- pack K: Ck[b*2048+kv][1024] -> Kp[b][h][kv32][kd][lane][8] ----------------
// chunk[j] = K[b][kv32*32 + l31][h*64 + kd*16 + hi*8 + j]
__global__ __launch_bounds__(256) void k_packK(const u16* __restrict__ Ck,
                                               u16* __restrict__ Kp) {
  int flat = blockIdx.x * 256 + threadIdx.x;   // 524288 chunks
  int lane = flat & 63, kd = (flat >> 6) & 3, kt = (flat >> 8) & 63;
  int h = (flat >> 14) & 15, b = flat >> 18;
  int l31 = lane & 31, hi = lane >> 5;
  const u16* src = &Ck[(size_t)(b * 2048 + kt * 32 + l31) * 1024 + h * 64 + kd * 16 + hi * 8];
  ((u16x8*)Kp)[flat] = *(const u16x8*)src;
}

// ---------------- pack V: Cv[b*2048+kv][1024] -> Vp[b][h][kv64][dvh][ks][lane][8] ----------------
// chunk[j] = V[b][kv64*64 + ks*16 + hi*8 + j][h*64 + dvh*32 + l31]
__global__ __launch_bounds__(256) void k_packV(const u16* __restrict__ Cv,
                                               u16* __restrict__ Vp) {
  int flat = blockIdx.x * 256 + threadIdx.x;   // 524288 chunks
  int lane = flat & 63, ks = (flat >> 6) & 3, dvh = (flat >> 8) & 1;
  int kt = (flat >> 9) & 31, h = (flat >> 14) & 15, b = flat >> 18;
  int l31 = lane & 31, hi = lane >> 5;
  const u16* src = &Cv[(size_t)(b * 2048 + kt * 64 + ks * 16 + hi * 8) * 1024 + h * 64 + dvh * 32 + l31];
  u16x8 o;
#pragma unroll
  for (int j = 0; j < 8; ++j) o[j] = src[(size_t)j * 1024];
  ((u16x8*)Vp)[flat] = o;
}

// ---------------- GEMM: C[M,N] = A[M,K]*Bt[N,K]^T + bias, 128x128 tile ----------------
struct GemmSet { const u16* A; const u16* Bt; const float* bias; void* C; };
struct GemmArgs { GemmSet s[3]; };

template <int OUTF32>
__global__ __launch_bounds__(256) void k_gemm_bt(GemmArgs ga) {
  constexpr int K = 1024, N = 1024;
  __shared__ __align__(16) u16 Al[128 * 32];
  __shared__ __align__(16) u16 Bl[128 * 32];
  int mat = blockIdx.x >> 8;
  int t = blockIdx.x & 255;
  int m0 = (t & 31) << 7;
  int n0 = (t >> 5) << 7;
  const u16* A = ga.s[mat].A;
  const u16* Bt = ga.s[mat].Bt;
  int lane = threadIdx.x & 63, w = threadIdx.x >> 6;
  int g = lane >> 4, cl = lane & 15;
  int wr = w >> 1, wc = w & 1;
  f32x4 zero4 = {0.f, 0.f, 0.f, 0.f};
  f32x4 acc[4][4];
#pragma unroll
  for (int i = 0; i < 4; ++i)
#pragma unroll
    for (int j = 0; j < 4; ++j) acc[i][j] = zero4;

  int srow0 = w * 32 + (lane >> 2);
  int scol = (lane & 3) << 3;
  for (int kt = 0; kt < K / 32; ++kt) {
    int k0 = kt << 5;
#pragma unroll
    for (int c = 0; c < 2; ++c) {
      int row = srow0 + c * 16;
      gload_lds16(&A[(size_t)(m0 + row) * K + k0 + scol], &Al[w * 1024 + c * 512]);
      gload_lds16(&Bt[(size_t)(n0 + row) * K + k0 + scol], &Bl[w * 1024 + c * 512]);
    }
    __syncthreads();
    bf16x8 af[4], bfm[4];
#pragma unroll
    for (int i = 0; i < 4; ++i) {
      af[i]  = *(const bf16x8*)&Al[(wr * 64 + i * 16 + cl) * 32 + g * 8];
      bfm[i] = *(const bf16x8*)&Bl[(wc * 64 + i * 16 + cl) * 32 + g * 8];
    }
#pragma unroll
    for (int mi = 0; mi < 4; ++mi)
#pragma unroll
      for (int ni = 0; ni < 4; ++ni)
        acc[mi][ni] = __builtin_amdgcn_mfma_f32_16x16x32_bf16(af[mi], bfm[ni], acc[mi][ni], 0, 0, 0);
    __syncthreads();
  }
  const float* bias = ga.s[mat].bias;
#pragma unroll
  for (int ni = 0; ni < 4; ++ni) {
    int n = n0 + wc * 64 + ni * 16 + cl;
    float bv = bias[n];
#pragma unroll
    for (int mi = 0; mi < 4; ++mi) {
      int r0 = m0 + wr * 64 + mi * 16 + g * 4;
#pragma unroll
      for (int r = 0; r < 4; ++r) {
        float val = acc[mi][ni][r] + bv;
        if (OUTF32) ((float*)ga.s[mat].C)[(size_t)(r0 + r) * N + n] = val;
        else        ((u16*)ga.s[mat].C)[(size_t)(r0 + r) * N + n] = f2bf(val);
      }
    }
  }
}

// ---------------- flash attention, 32x32 swapped-QK^T, packed K/V ----------------
// Q: [B,S,1024] bf16. Kp/Vp: fragment-major packed (see pack kernels). O: [B,S,1024] bf16.
__global__ __launch_bounds__(256) void k_attn2(const u16* __restrict__ Q,
                                               const u16* __restrict__ Kp,
                                               const u16* __restrict__ Vp,
                                               u16* __restrict__ O) {
  int lane = threadIdx.x & 63, w = threadIdx.x >> 6;
  int l31 = lane & 31, hi = lane >> 5;
  int bx = blockIdx.x;
  int logical = (bx & 7) * 64 + (bx >> 3);   // group a head's q-tiles on one XCD
  int bh = logical >> 4, qt = logical & 15;
  int b = bh >> 4, h = bh & 15;
  const u16* Qb = Q + (size_t)b * S_LEN * DMODEL + h * 64;
  const u16* Kph = Kp + (size_t)(b * 16 + h) * (64 * 4 * 64 * 8);
  const u16* Vph = Vp + (size_t)(b * 16 + h) * (32 * 2 * 4 * 64 * 8);
  u16* Ob = O + (size_t)b * S_LEN * DMODEL + h * 64;
  int qbase = qt * 128 + w * 32;

  // Q as B-fragments: lane holds Q[qbase+l31][kd*16 + hi*8 + j], kd=0..3
  bf16x8 qf[4];
  const u16* qp = &Qb[(size_t)(qbase + l31) * DMODEL + hi * 8];
#pragma unroll
  for (int kd = 0; kd < 4; ++kd) qf[kd] = *(const bf16x8*)&qp[kd * 16];

  f32x16 zero16 = {0};
  f32x16 oa0 = zero16, oa1 = zero16;
  float m = -3.0e38f, lsum = 0.f;
  const float INVSQ = 0.125f;  // 1/sqrt(64)

  for (int kt = 0; kt < S_LEN / 64; ++kt) {
    const u16* kpt = Kph + (size_t)kt * 4096 + (size_t)lane * 8;  // 2 kv32-tiles of [4][64][8]
    const u16* vpt = Vph + (size_t)kt * 4096 + (size_t)lane * 8;  // [2 dvh][4 ks][64][8]
    // V B-fragments (issue early, fully coalesced: lane*16B contiguous)
    bf16x8 vf0[4], vf1[4];
#pragma unroll
    for (int ks = 0; ks < 4; ++ks) {
      vf0[ks] = *(const bf16x8*)&vpt[ks * 512];
      vf1[ks] = *(const bf16x8*)&vpt[2048 + ks * 512];
    }
    // QK^T: S^T tiles (kv x q), A = K rows, B = Q
    f32x16 s0 = zero16, s1 = zero16;
#pragma unroll
    for (int kd = 0; kd < 4; ++kd) {
      bf16x8 kfa = *(const bf16x8*)&kpt[kd * 512];
      bf16x8 kfb = *(const bf16x8*)&kpt[2048 + kd * 512];
      s0 = __builtin_amdgcn_mfma_f32_32x32x16_bf16(kfa, qf[kd], s0, 0, 0, 0);
      s1 = __builtin_amdgcn_mfma_f32_32x32x16_bf16(kfb, qf[kd], s1, 0, 0, 0);
    }

    // in-register row max (this lane's half of 64 kv values)
    float t0 = fmaxf(s0[0], s0[1]), t1 = fmaxf(s0[2], s0[3]);
    float t2 = fmaxf(s0[4], s0[5]), t3 = fmaxf(s0[6], s0[7]);
#pragma unroll
    for (int r = 8; r < 16; r += 4) {
      t0 = fmaxf(t0, fmaxf(s0[r], s0[r + 1]));
      t1 = fmaxf(t1, fmaxf(s0[r + 2], s0[r + 3]));
    }
#pragma unroll
    for (int r = 0; r < 16; r += 4) {
      t2 = fmaxf(t2, fmaxf(s1[r], s1[r + 1]));
      t3 = fmaxf(t3, fmaxf(s1[r + 2], s1[r + 3]));
    }
    float tm = fmaxf(fmaxf(t0, t1), fmaxf(t2, t3));

    // defer-max: rescale only when max grows beyond raw threshold 64 (p <= e^8)
    if (!__all(tm <= m + 64.0f)) {
      float tmf = fmaxf(tm, __shfl_xor(tm, 32, 64));
      float mnew = fmaxf(m, tmf);
      float alpha = __expf((m - mnew) * INVSQ);
#pragma unroll
      for (int r = 0; r < 16; ++r) {
        float ar = __shfl(alpha, ((r & 3) + 8 * (r >> 2)) + 4 * hi, 64);
        oa0[r] *= ar; oa1[r] *= ar;
      }
      lsum *= alpha;
      m = mnew;
    }

    // p = exp((s - m)/8), row sum
    float rs0 = 0.f, rs1 = 0.f;
#pragma unroll
    for (int r = 0; r < 16; ++r) {
      float p0 = __expf((s0[r] - m) * INVSQ);
      float p1 = __expf((s1[r] - m) * INVSQ);
      s0[r] = p0; s1[r] = p1;
      rs0 += p0; rs1 += p1;
    }
    float rs = rs0 + rs1;
    lsum += rs + __shfl_xor(rs, 32, 64);

    // pack P into PV A-fragments (kv = 16*ks + 8*hi + j per fragment)
    bf16x8 af[4];
    {
      u32 w0 = cvtpk(s0[0], s0[1]),  w1 = cvtpk(s0[2], s0[3]);
      u32 w2 = cvtpk(s0[4], s0[5]),  w3 = cvtpk(s0[6], s0[7]);
      u32 w4 = cvtpk(s0[8], s0[9]),  w5 = cvtpk(s0[10], s0[11]);
      u32 w6 = cvtpk(s0[12], s0[13]), w7 = cvtpk(s0[14], s0[15]);
      u32 x0 = __shfl_xor(w0, 32, 64), x1 = __shfl_xor(w1, 32, 64);
      u32 x2 = __shfl_xor(w2, 32, 64), x3 = __shfl_xor(w3, 32, 64);
      u32 x4 = __shfl_xor(w4, 32, 64), x5 = __shfl_xor(w5, 32, 64);
      u32 x6 = __shfl_xor(w6, 32, 64), x7 = __shfl_xor(w7, 32, 64);
      union { u32x4 u; bf16x8 v; } c0, c1;
      c0.u = u32x4{hi ? x2 : w0, hi ? x3 : w1, hi ? w2 : x0, hi ? w3 : x1};
      c1.u = u32x4{hi ? x6 : w4, hi ? x7 : w5, hi ? w6 : x4, hi ? w7 : x5};
      af[0] = c0.v; af[1] = c1.v;
    }
    {
      u32 w0 = cvtpk(s1[0], s1[1]),  w1 = cvtpk(s1[2], s1[3]);
      u32 w2 = cvtpk(s1[4], s1[5]),  w3 = cvtpk(s1[6], s1[7]);
      u32 w4 = cvtpk(s1[8], s1[9]),  w5 = cvtpk(s1[10], s1[11]);
      u32 w6 = cvtpk(s1[12], s1[13]), w7 = cvtpk(s1[14], s1[15]);
      u32 x0 = __shfl_xor(w0, 32, 64), x1 = __shfl_xor(w1, 32, 64);
      u32 x2 = __shfl_xor(w2, 32, 64), x3 = __shfl_xor(w3, 32, 64);
      u32 x4 = __shfl_xor(w4, 32, 64), x5 = __shfl_xor(w5, 32, 64);
      u32 x6 = __shfl_xor(w6, 32, 64), x7 = __shfl_xor(w7, 32, 64);
      union { u32x4 u; bf16x8 v; } c0, c1;
      c0.u = u32x4{hi ? x2 : w0, hi ? x3 : w1, hi ? w2 : x0, hi ? w3 : x1};
      c1.u = u32x4{hi ? x6 : w4, hi ? x7 : w5, hi ? w6 : x4, hi ? w7 : x5};
      af[2] = c0.v; af[3] = c1.v;
    }

    // PV: O += P * V   (A = P rows=q, B = V cols=dv)
#pragma unroll
    for (int ks = 0; ks < 4; ++ks) {
      oa0 = __builtin_amdgcn_mfma_f32_32x32x16_bf16(af[ks], vf0[ks], oa0, 0, 0, 0);
      oa1 = __builtin_amdgcn_mfma_f32_32x32x16_bf16(af[ks], vf1[ks], oa1, 0, 0, 0);
    }
  }

  // normalize and store: row q = qbase + (r&3)+8*(r>>2)+4*hi, col dv = nt*32 + l31
  float invl = 1.0f / lsum;
#pragma unroll
  for (int r = 0; r < 16; ++r) {
    float ir = __shfl(invl, ((r & 3) + 8 * (r >> 2)) + 4 * hi, 64);
    int row = qbase + ((r & 3) + 8 * (r >> 2)) + 4 * hi;
    Ob[(size_t)row * DMODEL + l31]      = f2bf(oa0[r] * ir);
    Ob[(size_t)row * DMODEL + 32 + l31] = f2bf(oa1[r] * ir);
  }
}

// ---------------- host ----------------
extern "C" void kernel_launch(void* const* d_in, const int* in_sizes, int n_in,
                              void* d_out, int out_size, void* d_ws, size_t ws_size,
                              hipStream_t stream) {
  const float* q  = (const float*)d_in[0];
  const float* k  = (const float*)d_in[1];
  const float* v  = (const float*)d_in[2];
  const float* Wq = (const float*)d_in[3];
  const float* bq = (const float*)d_in[4];
  const float* Wk = (const float*)d_in[5];
  const float* bk = (const float*)d_in[6];
  const float* Wv = (const float*)d_in[7];
  const float* bv = (const float*)d_in[8];
  const float* Wo = (const float*)d_in[9];
  const float* bo = (const float*)d_in[10];
  float* out = (float*)d_out;
  char* ws = (char*)d_ws;
  const size_t MB = 1024 * 1024;
  u16* wtq = (u16*)(ws + 0 * MB);
  u16* wtk = (u16*)(ws + 2 * MB);
  u16* wtv = (u16*)(ws + 4 * MB);
  u16* wto = (u16*)(ws + 6 * MB);
  u16* qb  = (u16*)(ws + 8 * MB);   // bf16 q  (dead after GEMM -> reused as Kp)
  u16* kb  = (u16*)(ws + 16 * MB);  // bf16 k  (dead after GEMM -> reused as O)
  u16* vb  = (u16*)(ws + 24 * MB);  // bf16 v  (dead after GEMM -> reused as Vp)
  u16* Cq  = (u16*)(ws + 32 * MB);
  u16* Ck  = (u16*)(ws + 40 * MB);
  u16* Cv  = (u16*)(ws + 48 * MB);
  u16* Kp  = qb;                    // alias
  u16* Vp  = vb;                    // alias
  u16* O   = kb;                    // alias

  const int NTOK = 2 * S_LEN * DMODEL;      // 4,194,304
  k_cvt<<<NTOK / 8 / 256, 256, 0, stream>>>(q, qb, NTOK / 8);
  k_cvt<<<NTOK / 8 / 256, 256, 0, stream>>>(k, kb, NTOK / 8);
  k_cvt<<<NTOK / 8 / 256, 256, 0, stream>>>(v, vb, NTOK / 8);

  k_twcvt<<<256, 256, 0, stream>>>(Wq, wtq, 1024, 1024);
  k_twcvt<<<256, 256, 0, stream>>>(Wk, wtk, 1024, 1024);
  k_twcvt<<<256, 256, 0, stream>>>(Wv, wtv, 1024, 1024);
  k_twcvt<<<256, 256, 0, stream>>>(Wo, wto, 1024, 1024);

  GemmArgs ga;
  ga.s[0] = {qb, wtq, bq, (void*)Cq};
  ga.s[1] = {kb, wtk, bk, (void*)Ck};
  ga.s[2] = {vb, wtv, bv, (void*)Cv};
  k_gemm_bt<0><<<768, 256, 0, stream>>>(ga);

  k_packK<<<2048, 256, 0, stream>>>(Ck, Kp);
  k_packV<<<2048, 256, 0, stream>>>(Cv, Vp);

  k_attn2<<<512, 256, 0, stream>>>(Cq, Kp, Vp, O);

  GemmArgs go;
  go.s[0] = {O, wto, bo, (void*)out};
  go.s[1] = go.s[0];
  go.s[2] = go.s[0];
  k_gemm_bt<1><<<256, 256, 0, stream>>>(go);
}

// Round 5
// 261.842 us; speedup vs baseline: 1.2384x; 1.0434x over previous
//
#include <hip/hip_runtime.h>

typedef unsigned short u16;
typedef unsigned int u32;
typedef __attribute__((ext_vector_type(4))) float f32x4;
typedef __attribute__((ext_vector_type(16))) float f32x16;
typedef __attribute__((ext_vector_type(8))) short bf16x8;
typedef __attribute__((ext_vector_type(4))) unsigned short u16x4;
typedef __attribute__((ext_vector_type(8))) unsigned short u16x8;
typedef __attribute__((ext_vector_type(4))) unsigned int u32x4;

#define S_LEN 2048
#define DMODEL 1024

__device__ __forceinline__ u16 f2bf(float f) {
  union { float f; unsigned int i; } c; c.f = f;
  unsigned int v = c.i + 0x7FFFu + ((c.i >> 16) & 1u);
  return (u16)(v >> 16);
}
__device__ __forceinline__ u32 cvtpk(float lo, float hi) {
  u32 r;
  asm("v_cvt_pk_bf16_f32 %0, %1, %2" : "=v"(r) : "v"(lo), "v"(hi));
  return r;
}

typedef const __attribute__((address_space(1))) void gv_t;
typedef __attribute__((address_space(3))) void lv_t;
__device__ __forceinline__ void gload_lds16(const void* g, void* l) {
  __builtin_amdgcn_global_load_lds((gv_t*)g, (lv_t*)l, 16, 0, 0);
}

// ---------------- f32 -> bf16 convert, 3 tensors fused ----------------
__global__ __launch_bounds__(256) void k_cvt3(const float* __restrict__ s0,
                                              const float* __restrict__ s1,
                                              const float* __restrict__ s2,
                                              u16* __restrict__ d0,
                                              u16* __restrict__ d1,
                                              u16* __restrict__ d2) {
  int i = blockIdx.x * 256 + threadIdx.x;    // 3 * 524288 chunks of 8
  int seg = i >> 19, idx = i & 524287;
  const float* s = seg == 0 ? s0 : (seg == 1 ? s1 : s2);
  u16* d = seg == 0 ? d0 : (seg == 1 ? d1 : d2);
  f32x4 a = ((const f32x4*)s)[idx * 2];
  f32x4 b = ((const f32x4*)s)[idx * 2 + 1];
  u16x8 o;
#pragma unroll
  for (int j = 0; j < 4; ++j) { o[j] = f2bf(a[j]); o[j + 4] = f2bf(b[j]); }
  ((u16x8*)d)[idx] = o;
}

// ---------------- weight transpose+convert, 4 weights fused ----------------
struct TwArgs { const float* src[4]; u16* dst[4]; };
__global__ __launch_bounds__(256) void k_twcvt4(TwArgs ta) {
  __shared__ u16 tile[64][68];
  int wsel = blockIdx.x >> 8;
  int bx = blockIdx.x & 255;
  const float* src = ta.src[wsel];
  u16* dst = ta.dst[wsel];
  const int R = 1024, C = 1024;
  int tr = bx >> 4, tc = bx & 15;
  int r0 = tr << 6, c0 = tc << 6;
  int t = threadIdx.x;
#pragma unroll
  for (int i = 0; i < 4; ++i) {
    int e = (t + i * 256) << 2;
    int rr = e >> 6, cc = e & 63;
    f32x4 v = *(const f32x4*)&src[(size_t)(r0 + rr) * C + (c0 + cc)];
#pragma unroll
    for (int j = 0; j < 4; ++j) tile[rr][cc + j] = f2bf(v[j]);
  }
  __syncthreads();
#pragma unroll
  for (int i = 0; i < 4; ++i) {
    int e = (t + i * 256) << 2;
    int rr = e >> 6, cc = e & 63;
    u16x4 v;
#pragma unroll
    for (int j = 0; j < 4; ++j) v[j] = tile[cc + j][rr];
    *(u16x4*)&dst[(size_t)(c0 + rr) * R + (r0 + cc)] = v;
  }
}

// ---------------- pack K & V into MFMA fragment-major layout (fused) ----------------
// Kp[b][h][kv32][kd][lane][8]: chunk[j] = K[b][kv32*32+l31][h*64+kd*16+hi*8+j]
// Vp[b][h][kv64][dvh][ks][lane][8]: chunk[j] = V[b][kv64*64+ks*16+hi*8+j][h*64+dvh*32+l31]
__global__ __launch_bounds__(256) void k_pack(const u16* __restrict__ Ck,
                                              const u16* __restrict__ Cv,
                                              u16* __restrict__ Kp,
                                              u16* __restrict__ Vp) {
  int bx = blockIdx.x;
  if (bx < 2048) {
    int flat = bx * 256 + threadIdx.x;
    int lane = flat & 63, kd = (flat >> 6) & 3, kt = (flat >> 8) & 63;
    int h = (flat >> 14) & 15, b = flat >> 18;
    int l31 = lane & 31, hi = lane >> 5;
    const u16* src = &Ck[(size_t)(b * 2048 + kt * 32 + l31) * 1024 + h * 64 + kd * 16 + hi * 8];
    ((u16x8*)Kp)[flat] = *(const u16x8*)src;
  } else {
    int flat = (bx - 2048) * 256 + threadIdx.x;
    int lane = flat & 63, ks = (flat >> 6) & 3, dvh = (flat >> 8) & 1;
    int kt = (flat >> 9) & 31, h = (flat >> 14) & 15, b = flat >> 18;
    int l31 = lane & 31, hi = lane >> 5;
    const u16* src = &Cv[(size_t)(b * 2048 + kt * 64 + ks * 16 + hi * 8) * 1024 + h * 64 + dvh * 32 + l31];
    u16x8 o;
#pragma unroll
    for (int j = 0; j < 8; ++j) o[j] = src[(size_t)j * 1024];
    ((u16x8*)Vp)[flat] = o;
  }
}

// ---------------- GEMM: C[M,N] = A[M,K]*Bt[N,K]^T + bias, 128x128 tile ----------------
struct GemmSet { const u16* A; const u16* Bt; const float* bias; void* C; };
struct GemmArgs { GemmSet s[3]; };

template <int OUTF32>
__global__ __launch_bounds__(256) void k_gemm_bt(GemmArgs ga) {
  constexpr int K = 1024, N = 1024;
  __shared__ __align__(16) u16 Al[128 * 32];
  __shared__ __align__(16) u16 Bl[128 * 32];
  int mat = blockIdx.x >> 8;
  int t = blockIdx.x & 255;
  int m0 = (t & 31) << 7;
  int n0 = (t >> 5) << 7;
  const u16* A = ga.s[mat].A;
  const u16* Bt = ga.s[mat].Bt;
  int lane = threadIdx.x & 63, w = threadIdx.x >> 6;
  int g = lane >> 4, cl = lane & 15;
  int wr = w >> 1, wc = w & 1;
  f32x4 zero4 = {0.f, 0.f, 0.f, 0.f};
  f32x4 acc[4][4];
#pragma unroll
  for (int i = 0; i < 4; ++i)
#pragma unroll
    for (int j = 0; j < 4; ++j) acc[i][j] = zero4;

  int srow0 = w * 32 + (lane >> 2);
  int scol = (lane & 3) << 3;
  for (int kt = 0; kt < K / 32; ++kt) {
    int k0 = kt << 5;
#pragma unroll
    for (int c = 0; c < 2; ++c) {
      int row = srow0 + c * 16;
      gload_lds16(&A[(size_t)(m0 + row) * K + k0 + scol], &Al[w * 1024 + c * 512]);
      gload_lds16(&Bt[(size_t)(n0 + row) * K + k0 + scol], &Bl[w * 1024 + c * 512]);
    }
    __syncthreads();
    bf16x8 af[4], bfm[4];
#pragma unroll
    for (int i = 0; i < 4; ++i) {
      af[i]  = *(const bf16x8*)&Al[(wr * 64 + i * 16 + cl) * 32 + g * 8];
      bfm[i] = *(const bf16x8*)&Bl[(wc * 64 + i * 16 + cl) * 32 + g * 8];
    }
#pragma unroll
    for (int mi = 0; mi < 4; ++mi)
#pragma unroll
      for (int ni = 0; ni < 4; ++ni)
        acc[mi][ni] = __builtin_amdgcn_mfma_f32_16x16x32_bf16(af[mi], bfm[ni], acc[mi][ni], 0, 0, 0);
    __syncthreads();
  }
  const float* bias = ga.s[mat].bias;
#pragma unroll
  for (int ni = 0; ni < 4; ++ni) {
    int n = n0 + wc * 64 + ni * 16 + cl;
    float bv = bias[n];
#pragma unroll
    for (int mi = 0; mi < 4; ++mi) {
      int r0 = m0 + wr * 64 + mi * 16 + g * 4;
#pragma unroll
      for (int r = 0; r < 4; ++r) {
        float val = acc[mi][ni][r] + bv;
        if (OUTF32) ((float*)ga.s[mat].C)[(size_t)(r0 + r) * N + n] = val;
        else        ((u16*)ga.s[mat].C)[(size_t)(r0 + r) * N + n] = f2bf(val);
      }
    }
  }
}

// ---------------- flash attention, 32x32 swapped-QK^T, packed K/V, kv-split x2 ----------------
// Block: 64 q-rows; waves 0-1 -> kv[0,1024), waves 2-3 -> kv[1024,2048); LDS merge.
__global__ __launch_bounds__(256) void k_attn3(const u16* __restrict__ Q,
                                               const u16* __restrict__ Kp,
                                               const u16* __restrict__ Vp,
                                               u16* __restrict__ O) {
  __shared__ __align__(16) float Ol[2][32][64];
  __shared__ float Ml[2][32][2];
  int lane = threadIdx.x & 63, w = threadIdx.x >> 6;
  int l31 = lane & 31, hi = lane >> 5;
  int half = w >> 1, sub = w & 1;
  int bx = blockIdx.x;
  int logical = (bx & 7) * 128 + (bx >> 3);   // 4 whole heads per XCD
  int bh = logical >> 5, qblk = logical & 31;
  int b = bh >> 4, h = bh & 15;
  const u16* Qb = Q + (size_t)b * S_LEN * DMODEL + h * 64;
  const u16* Kph = Kp + (size_t)(b * 16 + h) * (64 * 4 * 64 * 8);
  const u16* Vph = Vp + (size_t)(b * 16 + h) * (32 * 2 * 4 * 64 * 8);
  u16* Ob = O + (size_t)b * S_LEN * DMODEL + h * 64;
  int qbase = qblk * 64 + sub * 32;

  // Q as B-fragments: lane holds Q[qbase+l31][kd*16 + hi*8 + j], kd=0..3
  bf16x8 qf[4];
  const u16* qp = &Qb[(size_t)(qbase + l31) * DMODEL + hi * 8];
#pragma unroll
  for (int kd = 0; kd < 4; ++kd) qf[kd] = *(const bf16x8*)&qp[kd * 16];

  f32x16 zero16 = {0};
  f32x16 oa0 = zero16, oa1 = zero16;
  float m = -3.0e38f, lsum = 0.f;
  const float INVSQ = 0.125f;  // 1/sqrt(64)

  int kt0 = half * 16;
  for (int kt = kt0; kt < kt0 + 16; ++kt) {
    const u16* kpt = Kph + (size_t)kt * 4096 + (size_t)lane * 8;  // 2 kv32-tiles of [4][64][8]
    const u16* vpt = Vph + (size_t)kt * 4096 + (size_t)lane * 8;  // [2 dvh][4 ks][64][8]
    bf16x8 vf0[4], vf1[4];
#pragma unroll
    for (int ks = 0; ks < 4; ++ks) {
      vf0[ks] = *(const bf16x8*)&vpt[ks * 512];
      vf1[ks] = *(const bf16x8*)&vpt[2048 + ks * 512];
    }
    f32x16 s0 = zero16, s1 = zero16;
#pragma unroll
    for (int kd = 0; kd < 4; ++kd) {
      bf16x8 kfa = *(const bf16x8*)&kpt[kd * 512];
      bf16x8 kfb = *(const bf16x8*)&kpt[2048 + kd * 512];
      s0 = __builtin_amdgcn_mfma_f32_32x32x16_bf16(kfa, qf[kd], s0, 0, 0, 0);
      s1 = __builtin_amdgcn_mfma_f32_32x32x16_bf16(kfb, qf[kd], s1, 0, 0, 0);
    }

    // in-register row max (this lane's half of 64 kv values)
    float t0 = fmaxf(s0[0], s0[1]), t1 = fmaxf(s0[2], s0[3]);
    float t2 = fmaxf(s0[4], s0[5]), t3 = fmaxf(s0[6], s0[7]);
#pragma unroll
    for (int r = 8; r < 16; r += 4) {
      t0 = fmaxf(t0, fmaxf(s0[r], s0[r + 1]));
      t1 = fmaxf(t1, fmaxf(s0[r + 2], s0[r + 3]));
    }
#pragma unroll
    for (int r = 0; r < 16; r += 4) {
      t2 = fmaxf(t2, fmaxf(s1[r], s1[r + 1]));
      t3 = fmaxf(t3, fmaxf(s1[r + 2], s1[r + 3]));
    }
    float tm = fmaxf(fmaxf(t0, t1), fmaxf(t2, t3));

    // defer-max: rescale only when max grows beyond raw threshold 64 (p <= e^8)
    if (!__all(tm <= m + 64.0f)) {
      float tmf = fmaxf(tm, __shfl_xor(tm, 32, 64));
      float mnew = fmaxf(m, tmf);
      float alpha = __expf((m - mnew) * INVSQ);
#pragma unroll
      for (int r = 0; r < 16; ++r) {
        float ar = __shfl(alpha, ((r & 3) + 8 * (r >> 2)) + 4 * hi, 64);
        oa0[r] *= ar; oa1[r] *= ar;
      }
      lsum *= alpha;
      m = mnew;
    }

    // p = exp((s - m)/8), row sum
    float rs0 = 0.f, rs1 = 0.f;
#pragma unroll
    for (int r = 0; r < 16; ++r) {
      float p0 = __expf((s0[r] - m) * INVSQ);
      float p1 = __expf((s1[r] - m) * INVSQ);
      s0[r] = p0; s1[r] = p1;
      rs0 += p0; rs1 += p1;
    }
    float rs = rs0 + rs1;
    lsum += rs + __shfl_xor(rs, 32, 64);

    // pack P into PV A-fragments (kv = 16*ks + 8*hi + j per fragment)
    bf16x8 af[4];
    {
      u32 w0 = cvtpk(s0[0], s0[1]),  w1 = cvtpk(s0[2], s0[3]);
      u32 w2 = cvtpk(s0[4], s0[5]),  w3 = cvtpk(s0[6], s0[7]);
      u32 w4 = cvtpk(s0[8], s0[9]),  w5 = cvtpk(s0[10], s0[11]);
      u32 w6 = cvtpk(s0[12], s0[13]), w7 = cvtpk(s0[14], s0[15]);
      u32 x0 = __shfl_xor(w0, 32, 64), x1 = __shfl_xor(w1, 32, 64);
      u32 x2 = __shfl_xor(w2, 32, 64), x3 = __shfl_xor(w3, 32, 64);
      u32 x4 = __shfl_xor(w4, 32, 64), x5 = __shfl_xor(w5, 32, 64);
      u32 x6 = __shfl_xor(w6, 32, 64), x7 = __shfl_xor(w7, 32, 64);
      union { u32x4 u; bf16x8 v; } c0, c1;
      c0.u = u32x4{hi ? x2 : w0, hi ? x3 : w1, hi ? w2 : x0, hi ? w3 : x1};
      c1.u = u32x4{hi ? x6 : w4, hi ? x7 : w5, hi ? w6 : x4, hi ? w7 : x5};
      af[0] = c0.v; af[1] = c1.v;
    }
    {
      u32 w0 = cvtpk(s1[0], s1[1]),  w1 = cvtpk(s1[2], s1[3]);
      u32 w2 = cvtpk(s1[4], s1[5]),  w3 = cvtpk(s1[6], s1[7]);
      u32 w4 = cvtpk(s1[8], s1[9]),  w5 = cvtpk(s1[10], s1[11]);
      u32 w6 = cvtpk(s1[12], s1[13]), w7 = cvtpk(s1[14], s1[15]);
      u32 x0 = __shfl_xor(w0, 32, 64), x1 = __shfl_xor(w1, 32, 64);
      u32 x2 = __shfl_xor(w2, 32, 64), x3 = __shfl_xor(w3, 32, 64);
      u32 x4 = __shfl_xor(w4, 32, 64), x5 = __shfl_xor(w5, 32, 64);
      u32 x6 = __shfl_xor(w6, 32, 64), x7 = __shfl_xor(w7, 32, 64);
      union { u32x4 u; bf16x8 v; } c0, c1;
      c0.u = u32x4{hi ? x2 : w0, hi ? x3 : w1, hi ? w2 : x0, hi ? w3 : x1};
      c1.u = u32x4{hi ? x6 : w4, hi ? x7 : w5, hi ? w6 : x4, hi ? w7 : x5};
      af[2] = c0.v; af[3] = c1.v;
    }

    // PV: O += P * V
#pragma unroll
    for (int ks = 0; ks < 4; ++ks) {
      oa0 = __builtin_amdgcn_mfma_f32_32x32x16_bf16(af[ks], vf0[ks], oa0, 0, 0, 0);
      oa1 = __builtin_amdgcn_mfma_f32_32x32x16_bf16(af[ks], vf1[ks], oa1, 0, 0, 0);
    }
  }

  // ---- intra-block merge of the two kv-halves ----
  if (half == 1) {
#pragma unroll
    for (int r = 0; r < 16; ++r) {
      int q = ((r & 3) + 8 * (r >> 2)) + 4 * hi;
      Ol[sub][q][l31] = oa0[r];
      Ol[sub][q][l31 + 32] = oa1[r];
    }
    if (hi == 0) { Ml[sub][l31][0] = m; Ml[sub][l31][1] = lsum; }
  }
  __syncthreads();
  if (half == 0) {
    float m1 = Ml[sub][l31][0], l1 = Ml[sub][l31][1];
    float M = fmaxf(m, m1);
    float a0 = __expf((m - M) * INVSQ);
    float a1 = __expf((m1 - M) * INVSQ);
    float invl = 1.0f / (a0 * lsum + a1 * l1);
    float c0 = a0 * invl, c1 = a1 * invl;
#pragma unroll
    for (int r = 0; r < 16; ++r) {
      int q = ((r & 3) + 8 * (r >> 2)) + 4 * hi;
      float f0 = __shfl(c0, q, 64);
      float f1 = __shfl(c1, q, 64);
      int row = qbase + q;
      float o0 = oa0[r] * f0 + Ol[sub][q][l31] * f1;
      float o1 = oa1[r] * f0 + Ol[sub][q][l31 + 32] * f1;
      Ob[(size_t)row * DMODEL + l31]      = f2bf(o0);
      Ob[(size_t)row * DMODEL + 32 + l31] = f2bf(o1);
    }
  }
}

// ---------------- host ----------------
extern "C" void kernel_launch(void* const* d_in, const int* in_sizes, int n_in,
                              void* d_out, int out_size, void* d_ws, size_t ws_size,
                              hipStream_t stream) {
  const float* q  = (const float*)d_in[0];
  const float* k  = (const float*)d_in[1];
  const float* v  = (const float*)d_in[2];
  const float* Wq = (const float*)d_in[3];
  const float* bq = (const float*)d_in[4];
  const float* Wk = (const float*)d_in[5];
  const float* bk = (const float*)d_in[6];
  const float* Wv = (const float*)d_in[7];
  const float* bv = (const float*)d_in[8];
  const float* Wo = (const float*)d_in[9];
  const float* bo = (const float*)d_in[10];
  float* out = (float*)d_out;
  char* ws = (char*)d_ws;
  const size_t MB = 1024 * 1024;
  u16* wtq = (u16*)(ws + 0 * MB);
  u16* wtk = (u16*)(ws + 2 * MB);
  u16* wtv = (u16*)(ws + 4 * MB);
  u16* wto = (u16*)(ws + 6 * MB);
  u16* qb  = (u16*)(ws + 8 * MB);   // bf16 q  (dead after GEMM -> reused as Kp)
  u16* kb  = (u16*)(ws + 16 * MB);  // bf16 k  (dead after GEMM -> reused as O)
  u16* vb  = (u16*)(ws + 24 * MB);  // bf16 v  (dead after GEMM -> reused as Vp)
  u16* Cq  = (u16*)(ws + 32 * MB);
  u16* Ck  = (u16*)(ws + 40 * MB);
  u16* Cv  = (u16*)(ws + 48 * MB);
  u16* Kp  = qb;                    // alias
  u16* Vp  = vb;                    // alias
  u16* O   = kb;                    // alias

  k_cvt3<<<6144, 256, 0, stream>>>(q, k, v, qb, kb, vb);

  TwArgs ta;
  ta.src[0] = Wq; ta.src[1] = Wk; ta.src[2] = Wv; ta.src[3] = Wo;
  ta.dst[0] = wtq; ta.dst[1] = wtk; ta.dst[2] = wtv; ta.dst[3] = wto;
  k_twcvt4<<<1024, 256, 0, stream>>>(ta);

  GemmArgs ga;
  ga.s[0] = {qb, wtq, bq, (void*)Cq};
  ga.s[1] = {kb, wtk, bk, (void*)Ck};
  ga.s[2] = {vb, wtv, bv, (void*)Cv};
  k_gemm_bt<0><<<768, 256, 0, stream>>>(ga);

  k_pack<<<4096, 256, 0, stream>>>(Ck, Cv, Kp, Vp);

  k_attn3<<<1024, 256, 0, stream>>>(Cq, Kp, Vp, O);

  GemmArgs go;
  go.s[0] = {O, wto, bo, (void*)out};
  go.s[1] = go.s[0];
  go.s[2] = go.s[0];
  k_gemm_bt<1><<<256, 256, 0, stream>>>(go);
}

// Round 6
// 249.941 us; speedup vs baseline: 1.2974x; 1.0476x over previous
//
#include <hip/hip_runtime.h>

typedef unsigned short u16;
typedef unsigned int u32;
typedef __attribute__((ext_vector_type(4))) float f32x4;
typedef __attribute__((ext_vector_type(16))) float f32x16;
typedef __attribute__((ext_vector_type(8))) short bf16x8;
typedef __attribute__((ext_vector_type(4))) unsigned short u16x4;
typedef __attribute__((ext_vector_type(8))) unsigned short u16x8;
typedef __attribute__((ext_vector_type(4))) unsigned int u32x4;

#define S_LEN 2048
#define DMODEL 1024

__device__ __forceinline__ u16 f2bf(float f) {
  union { float f; unsigned int i; } c; c.f = f;
  unsigned int v = c.i + 0x7FFFu + ((c.i >> 16) & 1u);
  return (u16)(v >> 16);
}
__device__ __forceinline__ u32 cvtpk(float lo, float hi) {
  u32 r;
  asm("v_cvt_pk_bf16_f32 %0, %1, %2" : "=v"(r) : "v"(lo), "v"(hi));
  return r;
}
__device__ __forceinline__ float exp2v(float x) {
  float r;
  asm("v_exp_f32 %0, %1" : "=v"(r) : "v"(x));
  return r;
}

typedef const __attribute__((address_space(1))) void gv_t;
typedef __attribute__((address_space(3))) void lv_t;
__device__ __forceinline__ void gload_lds16(const void* g, void* l) {
  __builtin_amdgcn_global_load_lds((gv_t*)g, (lv_t*)l, 16, 0, 0);
}

// ---------------- f32 -> bf16 convert, 3 tensors fused ----------------
__global__ __launch_bounds__(256) void k_cvt3(const float* __restrict__ s0,
                                              const float* __restrict__ s1,
                                              const float* __restrict__ s2,
                                              u16* __restrict__ d0,
                                              u16* __restrict__ d1,
                                              u16* __restrict__ d2) {
  int i = blockIdx.x * 256 + threadIdx.x;    // 3 * 524288 chunks of 8
  int seg = i >> 19, idx = i & 524287;
  const float* s = seg == 0 ? s0 : (seg == 1 ? s1 : s2);
  u16* d = seg == 0 ? d0 : (seg == 1 ? d1 : d2);
  f32x4 a = ((const f32x4*)s)[idx * 2];
  f32x4 b = ((const f32x4*)s)[idx * 2 + 1];
  u16x8 o;
#pragma unroll
  for (int j = 0; j < 4; ++j) { o[j] = f2bf(a[j]); o[j + 4] = f2bf(b[j]); }
  ((u16x8*)d)[idx] = o;
}

// ---------------- weight transpose+convert, 4 weights fused ----------------
struct TwArgs { const float* src[4]; u16* dst[4]; };
__global__ __launch_bounds__(256) void k_twcvt4(TwArgs ta) {
  __shared__ u16 tile[64][68];
  int wsel = blockIdx.x >> 8;
  int bx = blockIdx.x & 255;
  const float* src = ta.src[wsel];
  u16* dst = ta.dst[wsel];
  const int R = 1024, C = 1024;
  int tr = bx >> 4, tc = bx & 15;
  int r0 = tr << 6, c0 = tc << 6;
  int t = threadIdx.x;
#pragma unroll
  for (int i = 0; i < 4; ++i) {
    int e = (t + i * 256) << 2;
    int rr = e >> 6, cc = e & 63;
    f32x4 v = *(const f32x4*)&src[(size_t)(r0 + rr) * C + (c0 + cc)];
#pragma unroll
    for (int j = 0; j < 4; ++j) tile[rr][cc + j] = f2bf(v[j]);
  }
  __syncthreads();
#pragma unroll
  for (int i = 0; i < 4; ++i) {
    int e = (t + i * 256) << 2;
    int rr = e >> 6, cc = e & 63;
    u16x4 v;
#pragma unroll
    for (int j = 0; j < 4; ++j) v[j] = tile[cc + j][rr];
    *(u16x4*)&dst[(size_t)(c0 + rr) * R + (r0 + cc)] = v;
  }
}

// ---------------- pack K & V into MFMA fragment-major layout (fused) ----------------
// Kp[b][h][kv32][kd][lane][8]: chunk[j] = K[b][kv32*32+l31][h*64+kd*16+hi*8+j]
// Vp[b][h][kv64][dvh][ks][lane][8]: chunk[j] = V[b][kv64*64+ks*16+hi*8+j][h*64+dvh*32+l31]
__global__ __launch_bounds__(256) void k_pack(const u16* __restrict__ Ck,
                                              const u16* __restrict__ Cv,
                                              u16* __restrict__ Kp,
                                              u16* __restrict__ Vp) {
  int bx = blockIdx.x;
  if (bx < 2048) {
    int flat = bx * 256 + threadIdx.x;
    int lane = flat & 63, kd = (flat >> 6) & 3, kt = (flat >> 8) & 63;
    int h = (flat >> 14) & 15, b = flat >> 18;
    int l31 = lane & 31, hi = lane >> 5;
    const u16* src = &Ck[(size_t)(b * 2048 + kt * 32 + l31) * 1024 + h * 64 + kd * 16 + hi * 8];
    ((u16x8*)Kp)[flat] = *(const u16x8*)src;
  } else {
    int flat = (bx - 2048) * 256 + threadIdx.x;
    int lane = flat & 63, ks = (flat >> 6) & 3, dvh = (flat >> 8) & 1;
    int kt = (flat >> 9) & 31, h = (flat >> 14) & 15, b = flat >> 18;
    int l31 = lane & 31, hi = lane >> 5;
    const u16* src = &Cv[(size_t)(b * 2048 + kt * 64 + ks * 16 + hi * 8) * 1024 + h * 64 + dvh * 32 + l31];
    u16x8 o;
#pragma unroll
    for (int j = 0; j < 8; ++j) o[j] = src[(size_t)j * 1024];
    ((u16x8*)Vp)[flat] = o;
  }
}

// ---------------- GEMM: C[M,N] = A[M,K]*Bt[N,K]^T + bias, 128x128 tile ----------------
struct GemmSet { const u16* A; const u16* Bt; const float* bias; void* C; };
struct GemmArgs { GemmSet s[3]; };

template <int OUTF32>
__global__ __launch_bounds__(256) void k_gemm_bt(GemmArgs ga) {
  constexpr int K = 1024, N = 1024;
  __shared__ __align__(16) u16 Al[128 * 32];
  __shared__ __align__(16) u16 Bl[128 * 32];
  int mat = blockIdx.x >> 8;
  int t = blockIdx.x & 255;
  int m0 = (t & 31) << 7;
  int n0 = (t >> 5) << 7;
  const u16* A = ga.s[mat].A;
  const u16* Bt = ga.s[mat].Bt;
  int lane = threadIdx.x & 63, w = threadIdx.x >> 6;
  int g = lane >> 4, cl = lane & 15;
  int wr = w >> 1, wc = w & 1;
  f32x4 zero4 = {0.f, 0.f, 0.f, 0.f};
  f32x4 acc[4][4];
#pragma unroll
  for (int i = 0; i < 4; ++i)
#pragma unroll
    for (int j = 0; j < 4; ++j) acc[i][j] = zero4;

  int srow0 = w * 32 + (lane >> 2);
  int scol = (lane & 3) << 3;
  for (int kt = 0; kt < K / 32; ++kt) {
    int k0 = kt << 5;
#pragma unroll
    for (int c = 0; c < 2; ++c) {
      int row = srow0 + c * 16;
      gload_lds16(&A[(size_t)(m0 + row) * K + k0 + scol], &Al[w * 1024 + c * 512]);
      gload_lds16(&Bt[(size_t)(n0 + row) * K + k0 + scol], &Bl[w * 1024 + c * 512]);
    }
    __syncthreads();
    bf16x8 af[4], bfm[4];
#pragma unroll
    for (int i = 0; i < 4; ++i) {
      af[i]  = *(const bf16x8*)&Al[(wr * 64 + i * 16 + cl) * 32 + g * 8];
      bfm[i] = *(const bf16x8*)&Bl[(wc * 64 + i * 16 + cl) * 32 + g * 8];
    }
#pragma unroll
    for (int mi = 0; mi < 4; ++mi)
#pragma unroll
      for (int ni = 0; ni < 4; ++ni)
        acc[mi][ni] = __builtin_amdgcn_mfma_f32_16x16x32_bf16(af[mi], bfm[ni], acc[mi][ni], 0, 0, 0);
    __syncthreads();
  }
  const float* bias = ga.s[mat].bias;
#pragma unroll
  for (int ni = 0; ni < 4; ++ni) {
    int n = n0 + wc * 64 + ni * 16 + cl;
    float bv = bias[n];
#pragma unroll
    for (int mi = 0; mi < 4; ++mi) {
      int r0 = m0 + wr * 64 + mi * 16 + g * 4;
#pragma unroll
      for (int r = 0; r < 4; ++r) {
        float val = acc[mi][ni][r] + bv;
        if (OUTF32) ((float*)ga.s[mat].C)[(size_t)(r0 + r) * N + n] = val;
        else        ((u16*)ga.s[mat].C)[(size_t)(r0 + r) * N + n] = f2bf(val);
      }
    }
  }
}

// ---------------- flash attention: 32x32 swapped-QK^T, packed K/V, kv-split x2,
// register-dieted + forced 4 waves/SIMD ----------------
__global__ __launch_bounds__(256, 4) void k_attn4(const u16* __restrict__ Q,
                                                  const u16* __restrict__ Kp,
                                                  const u16* __restrict__ Vp,
                                                  u16* __restrict__ O) {
  __shared__ __align__(16) float Ol[2][32][64];
  __shared__ float Ml[2][32][2];
  int lane = threadIdx.x & 63, w = threadIdx.x >> 6;
  int l31 = lane & 31, hi = lane >> 5;
  int half = w >> 1, sub = w & 1;
  int bx = blockIdx.x;
  int logical = (bx & 7) * 128 + (bx >> 3);   // 4 whole heads per XCD
  int bh = logical >> 5, qblk = logical & 31;
  int b = bh >> 4, h = bh & 15;
  const u16* Qb = Q + (size_t)b * S_LEN * DMODEL + h * 64;
  const u16* Kph = Kp + (size_t)(b * 16 + h) * (64 * 4 * 64 * 8);
  const u16* Vph = Vp + (size_t)(b * 16 + h) * (32 * 2 * 4 * 64 * 8);
  u16* Ob = O + (size_t)b * S_LEN * DMODEL + h * 64;
  int qbase = qblk * 64 + sub * 32;

  // Q as B-fragments: lane holds Q[qbase+l31][kd*16 + hi*8 + j], kd=0..3
  bf16x8 qf[4];
  const u16* qp = &Qb[(size_t)(qbase + l31) * DMODEL + hi * 8];
#pragma unroll
  for (int kd = 0; kd < 4; ++kd) qf[kd] = *(const bf16x8*)&qp[kd * 16];

  f32x16 zero16 = {0};
  f32x16 oa0 = zero16, oa1 = zero16;
  float m = -3.0e38f, lsum = 0.f;
  const float INVSQ = 0.125f;               // 1/sqrt(64)
  const float C2 = 0.125f * 1.44269504f;    // to exp2 domain

  int kt0 = half * 16;
  for (int kt = kt0; kt < kt0 + 16; ++kt) {
    const u16* kpt = Kph + (size_t)kt * 4096 + (size_t)lane * 8;  // 2 kv32-tiles of [4][64][8]
    const u16* vpt = Vph + (size_t)kt * 4096 + (size_t)lane * 8;  // [2 dvh][4 ks][64][8]

    // QK^T: S^T tiles (kv x q), A = K rows, B = Q
    f32x16 s0 = zero16, s1 = zero16;
#pragma unroll
    for (int kd = 0; kd < 4; ++kd) {
      bf16x8 kfa = *(const bf16x8*)&kpt[kd * 512];
      bf16x8 kfb = *(const bf16x8*)&kpt[2048 + kd * 512];
      s0 = __builtin_amdgcn_mfma_f32_32x32x16_bf16(kfa, qf[kd], s0, 0, 0, 0);
      s1 = __builtin_amdgcn_mfma_f32_32x32x16_bf16(kfb, qf[kd], s1, 0, 0, 0);
    }

    // in-register row max (this lane's half of 64 kv values)
    float t0 = fmaxf(s0[0], s0[1]), t1 = fmaxf(s0[2], s0[3]);
    float t2 = fmaxf(s0[4], s0[5]), t3 = fmaxf(s0[6], s0[7]);
#pragma unroll
    for (int r = 8; r < 16; r += 4) {
      t0 = fmaxf(t0, fmaxf(s0[r], s0[r + 1]));
      t1 = fmaxf(t1, fmaxf(s0[r + 2], s0[r + 3]));
    }
#pragma unroll
    for (int r = 0; r < 16; r += 4) {
      t2 = fmaxf(t2, fmaxf(s1[r], s1[r + 1]));
      t3 = fmaxf(t3, fmaxf(s1[r + 2], s1[r + 3]));
    }
    float tm = fmaxf(fmaxf(t0, t1), fmaxf(t2, t3));

    // defer-max: rescale only when max grows beyond raw threshold 64 (p <= e^8)
    if (!__all(tm <= m + 64.0f)) {
      float tmf = fmaxf(tm, __shfl_xor(tm, 32, 64));
      float mnew = fmaxf(m, tmf);
      float alpha = __expf((m - mnew) * INVSQ);
#pragma unroll
      for (int r = 0; r < 16; ++r) {
        float ar = __shfl(alpha, ((r & 3) + 8 * (r >> 2)) + 4 * hi, 64);
        oa0[r] *= ar; oa1[r] *= ar;
      }
      lsum *= alpha;
      m = mnew;
    }

    // V fragment loads issued here: ~300 VALU-cycles of softmax/pack below cover L2 latency
    bf16x8 vf0[4], vf1[4];
#pragma unroll
    for (int ks = 0; ks < 4; ++ks) {
      vf0[ks] = *(const bf16x8*)&vpt[ks * 512];
      vf1[ks] = *(const bf16x8*)&vpt[2048 + ks * 512];
    }

    // streaming exp2 + pack: p = exp2(s*C2 - m*C2); s regs die pairwise
    float mc = m * C2;
    float rs = 0.f;
    bf16x8 af[4];
#pragma unroll
    for (int tile = 0; tile < 2; ++tile) {
      const f32x16& sv = tile ? s1 : s0;
#pragma unroll
      for (int hq = 0; hq < 2; ++hq) {   // af[tile*2+hq] from sv[hq*8 .. hq*8+7]
        float p0 = exp2v(__builtin_fmaf(sv[hq * 8 + 0], C2, -mc));
        float p1 = exp2v(__builtin_fmaf(sv[hq * 8 + 1], C2, -mc));
        rs += p0 + p1;
        u32 w0 = cvtpk(p0, p1);
        p0 = exp2v(__builtin_fmaf(sv[hq * 8 + 2], C2, -mc));
        p1 = exp2v(__builtin_fmaf(sv[hq * 8 + 3], C2, -mc));
        rs += p0 + p1;
        u32 w1 = cvtpk(p0, p1);
        p0 = exp2v(__builtin_fmaf(sv[hq * 8 + 4], C2, -mc));
        p1 = exp2v(__builtin_fmaf(sv[hq * 8 + 5], C2, -mc));
        rs += p0 + p1;
        u32 w2 = cvtpk(p0, p1);
        p0 = exp2v(__builtin_fmaf(sv[hq * 8 + 6], C2, -mc));
        p1 = exp2v(__builtin_fmaf(sv[hq * 8 + 7], C2, -mc));
        rs += p0 + p1;
        u32 w3 = cvtpk(p0, p1);
        u32 x0 = __shfl_xor(w0, 32, 64), x1 = __shfl_xor(w1, 32, 64);
        u32 x2 = __shfl_xor(w2, 32, 64), x3 = __shfl_xor(w3, 32, 64);
        union { u32x4 u; bf16x8 v; } c;
        c.u = u32x4{hi ? x2 : w0, hi ? x3 : w1, hi ? w2 : x0, hi ? w3 : x1};
        af[tile * 2 + hq] = c.v;
      }
    }
    lsum += rs + __shfl_xor(rs, 32, 64);

    // PV: O += P * V
#pragma unroll
    for (int ks = 0; ks < 4; ++ks) {
      oa0 = __builtin_amdgcn_mfma_f32_32x32x16_bf16(af[ks], vf0[ks], oa0, 0, 0, 0);
      oa1 = __builtin_amdgcn_mfma_f32_32x32x16_bf16(af[ks], vf1[ks], oa1, 0, 0, 0);
    }
  }

  // ---- intra-block merge of the two kv-halves ----
  if (half == 1) {
#pragma unroll
    for (int r = 0; r < 16; ++r) {
      int q = ((r & 3) + 8 * (r >> 2)) + 4 * hi;
      Ol[sub][q][l31] = oa0[r];
      Ol[sub][q][l31 + 32] = oa1[r];
    }
    if (hi == 0) { Ml[sub][l31][0] = m; Ml[sub][l31][1] = lsum; }
  }
  __syncthreads();
  if (half == 0) {
    float m1 = Ml[sub][l31][0], l1 = Ml[sub][l31][1];
    float M = fmaxf(m, m1);
    float a0 = __expf((m - M) * INVSQ);
    float a1 = __expf((m1 - M) * INVSQ);
    float invl = 1.0f / (a0 * lsum + a1 * l1);
    float c0 = a0 * invl, c1 = a1 * invl;
#pragma unroll
    for (int r = 0; r < 16; ++r) {
      int q = ((r & 3) + 8 * (r >> 2)) + 4 * hi;
      float f0 = __shfl(c0, q, 64);
      float f1 = __shfl(c1, q, 64);
      int row = qbase + q;
      float o0 = oa0[r] * f0 + Ol[sub][q][l31] * f1;
      float o1 = oa1[r] * f0 + Ol[sub][q][l31 + 32] * f1;
      Ob[(size_t)row * DMODEL + l31]      = f2bf(o0);
      Ob[(size_t)row * DMODEL + 32 + l31] = f2bf(o1);
    }
  }
}

// ---------------- host ----------------
extern "C" void kernel_launch(void* const* d_in, const int* in_sizes, int n_in,
                              void* d_out, int out_size, void* d_ws, size_t ws_size,
                              hipStream_t stream) {
  const float* q  = (const float*)d_in[0];
  const float* k  = (const float*)d_in[1];
  const float* v  = (const float*)d_in[2];
  const float* Wq = (const float*)d_in[3];
  const float* bq = (const float*)d_in[4];
  const float* Wk = (const float*)d_in[5];
  const float* bk = (const float*)d_in[6];
  const float* Wv = (const float*)d_in[7];
  const float* bv = (const float*)d_in[8];
  const float* Wo = (const float*)d_in[9];
  const float* bo = (const float*)d_in[10];
  float* out = (float*)d_out;
  char* ws = (char*)d_ws;
  const size_t MB = 1024 * 1024;
  u16* wtq = (u16*)(ws + 0 * MB);
  u16* wtk = (u16*)(ws + 2 * MB);
  u16* wtv = (u16*)(ws + 4 * MB);
  u16* wto = (u16*)(ws + 6 * MB);
  u16* qb  = (u16*)(ws + 8 * MB);   // bf16 q  (dead after GEMM -> reused as Kp)
  u16* kb  = (u16*)(ws + 16 * MB);  // bf16 k  (dead after GEMM -> reused as O)
  u16* vb  = (u16*)(ws + 24 * MB);  // bf16 v  (dead after GEMM -> reused as Vp)
  u16* Cq  = (u16*)(ws + 32 * MB);
  u16* Ck  = (u16*)(ws + 40 * MB);
  u16* Cv  = (u16*)(ws + 48 * MB);
  u16* Kp  = qb;                    // alias
  u16* Vp  = vb;                    // alias
  u16* O   = kb;                    // alias

  k_cvt3<<<6144, 256, 0, stream>>>(q, k, v, qb, kb, vb);

  TwArgs ta;
  ta.src[0] = Wq; ta.src[1] = Wk; ta.src[2] = Wv; ta.src[3] = Wo;
  ta.dst[0] = wtq; ta.dst[1] = wtk; ta.dst[2] = wtv; ta.dst[3] = wto;
  k_twcvt4<<<1024, 256, 0, stream>>>(ta);

  GemmArgs ga;
  ga.s[0] = {qb, wtq, bq, (void*)Cq};
  ga.s[1] = {kb, wtk, bk, (void*)Ck};
  ga.s[2] = {vb, wtv, bv, (void*)Cv};
  k_gemm_bt<0><<<768, 256, 0, stream>>>(ga);

  k_pack<<<4096, 256, 0, stream>>>(Ck, Cv, Kp, Vp);

  k_attn4<<<1024, 256, 0, stream>>>(Cq, Kp, Vp, O);

  GemmArgs go;
  go.s[0] = {O, wto, bo, (void*)out};
  go.s[1] = go.s[0];
  go.s[2] = go.s[0];
  k_gemm_bt<1><<<256, 256, 0, stream>>>(go);
}